// Round 2
// baseline (1290.074 us; speedup 1.0000x reference)
//
#include <hip/hip_runtime.h>
#include <math.h>

// ---------------------------------------------------------------------------
// DCTFrequencyEncoder: DCT2 -> mask(112x112) -> conv3x3(1->64)+BN+ReLU ->
// conv3x3(64->128)+BN+ReLU -> spatial mean -> linear(128->256)
//
// Exploits mask sparsity: conv2 output is non-constant only on A=[0,114)^2;
// outside A it takes one of 8 analytic per-channel constants.
// Round-1 fix: conv2 grid-splits over OUTPUT channels (BN+ReLU is per-oc
// elementwise -> exact), never over input channels (ReLU nonlinearity).
// ---------------------------------------------------------------------------

#define NPIX 224
#define KEEP 112
#define H1DIM 115     // h1 computed on [0,115)^2
#define ADIM 114      // region A

// ---- basis: B[k][n] = 2*cos(pi*k*(2n+1)/448), plus transpose ----
__global__ void basis_kernel(float* __restrict__ B, float* __restrict__ Bt) {
    int idx = blockIdx.x * 256 + threadIdx.x;
    if (idx >= NPIX * NPIX) return;
    int k = idx / NPIX, n = idx - k * NPIX;
    double ang = 3.14159265358979323846 * (double)k * (2.0 * n + 1.0) / (2.0 * NPIX);
    float v = (float)(2.0 * cos(ang));
    B[k * NPIX + n] = v;
    Bt[n * NPIX + k] = v;
}

// ---- DCT along W: tmp1[b*224+h][kw<112] = sum_w x[b,h,w]*B[kw,w] ----
__global__ __launch_bounds__(128) void dct_w_kernel(const float* __restrict__ x,
                                                    const float* __restrict__ Bt,
                                                    float* __restrict__ tmp1) {
    int bh = blockIdx.x;  // b*224 + h
    __shared__ float xr[NPIX];
    const float* row = x + (size_t)bh * NPIX;
    for (int i = threadIdx.x; i < NPIX; i += 128) xr[i] = row[i];
    __syncthreads();
    int kw = threadIdx.x;
    if (kw >= KEEP) return;
    float s = 0.f;
    for (int w = 0; w < NPIX; ++w) s = fmaf(xr[w], Bt[w * NPIX + kw], s);
    tmp1[(size_t)bh * KEEP + kw] = s;
}

// ---- DCT along H: Xd[b][kh<112][kw<112] = sum_h tmp1[b][h][kw]*B[kh,h] ----
__global__ __launch_bounds__(128) void dct_h_kernel(const float* __restrict__ tmp1,
                                                    const float* __restrict__ B,
                                                    float* __restrict__ Xd) {
    int kh = blockIdx.x;   // [0,112)
    int b  = blockIdx.y;   // [0,32)
    int kw = threadIdx.x;
    if (kw >= KEEP) return;
    const float* t = tmp1 + (size_t)b * NPIX * KEEP;
    const float* Bk = B + (size_t)kh * NPIX;
    float s = 0.f;
    for (int h = 0; h < NPIX; ++h) s = fmaf(t[h * KEEP + kw], Bk[h], s);
    Xd[((size_t)b * KEEP + kh) * KEEP + kw] = s;
}

// ---- c1[ic] = relu(bn1(b1)) : conv1 output where input window is all-zero ----
__global__ void prep_c1_kernel(const float* __restrict__ b1, const float* __restrict__ g1,
                               const float* __restrict__ be1, const float* __restrict__ m1,
                               const float* __restrict__ v1, float* __restrict__ c1) {
    int i = threadIdx.x;
    if (i < 64) {
        float sc = g1[i] * rsqrtf(v1[i] + 1e-5f);
        c1[i] = fmaxf((b1[i] - m1[i]) * sc + be1[i], 0.f);
    }
}

// ---- P[oc][tap] = sum_ic w2[oc,ic,tap] * c1[ic] ----
__global__ void prep_P_kernel(const float* __restrict__ w2, const float* __restrict__ c1,
                              float* __restrict__ P) {
    int idx = blockIdx.x * 256 + threadIdx.x;
    if (idx >= 128 * 9) return;
    int oc = idx / 9, tap = idx - oc * 9;
    float s = 0.f;
    for (int ic = 0; ic < 64; ++ic) s = fmaf(w2[((size_t)oc * 64 + ic) * 9 + tap], c1[ic], s);
    P[idx] = s;
}

// ---- w2t[ic][tap][oc] = w2[oc][ic][tap]  (for contiguous loads) ----
__global__ void transpose_w2_kernel(const float* __restrict__ w2, float* __restrict__ w2t) {
    int idx = blockIdx.x * 256 + threadIdx.x;
    if (idx >= 128 * 64 * 9) return;
    int tap = idx % 9;
    int t2 = idx / 9;
    int ic = t2 & 63;
    int oc = t2 >> 6;
    w2t[((size_t)ic * 9 + tap) * 128 + oc] = w2[idx];
}

// ---- conv1 + BN + ReLU on [0,115)^2, planar layout h1[b][ic][r][c] ----
__global__ __launch_bounds__(256) void conv1_kernel(const float* __restrict__ Xd,
                                                    const float* __restrict__ w1,
                                                    const float* __restrict__ b1,
                                                    const float* __restrict__ g1,
                                                    const float* __restrict__ be1,
                                                    const float* __restrict__ m1,
                                                    const float* __restrict__ v1,
                                                    float* __restrict__ h1) {
    int b = blockIdx.z, ic = blockIdx.y;
    int p = blockIdx.x * 256 + threadIdx.x;
    if (p >= H1DIM * H1DIM) return;
    int r = p / H1DIM, c = p - r * H1DIM;
    const float* X = Xd + (size_t)b * KEEP * KEEP;
    float s = 0.f;
#pragma unroll
    for (int ky = 0; ky < 3; ++ky) {
#pragma unroll
        for (int kx = 0; kx < 3; ++kx) {
            int rr = r + ky - 1, cc = c + kx - 1;
            float xv = (rr >= 0 && rr < KEEP && cc >= 0 && cc < KEEP) ? X[rr * KEEP + cc] : 0.f;
            s = fmaf(xv, w1[ic * 9 + ky * 3 + kx], s);
        }
    }
    float sc = g1[ic] * rsqrtf(v1[ic] + 1e-5f);
    float val = (s + b1[ic] - m1[ic]) * sc + be1[ic];
    h1[((size_t)b * 64 + ic) * (H1DIM * H1DIM) + p] = fmaxf(val, 0.f);
}

// ---- conv2 + BN + ReLU fused with spatial partial-sum over region A ----
// grid: (4 = tile_c*2+ocHalf, 8 = tile_r, 32 = b), block 256.
// tile: 16 rows x 64 cols; thread (ty=wave, tx=lane) covers rows ty+{0,4,8,12}, col tx.
// Each block: ALL 64 input channels, 64 of the 128 output channels.
__global__ __launch_bounds__(256, 4) void conv2_fused_kernel(
    const float* __restrict__ h1, const float* __restrict__ w2t,
    const float* __restrict__ b2, const float* __restrict__ g2,
    const float* __restrict__ be2, const float* __restrict__ m2,
    const float* __restrict__ v2, float* __restrict__ partial) {
    const int bx = blockIdx.x;
    const int tile_c = bx >> 1, ocHalf = bx & 1;
    const int tile_r = blockIdx.y;
    const int b = blockIdx.z;
    const int tid = threadIdx.x;
    const int tx = tid & 63;
    const int ty = tid >> 6;

    const int R0 = tile_r * 16;
    const int C0 = tile_c * 64;

    __shared__ float hT[8][18][66];

    const float* __restrict__ h1b = h1 + (size_t)b * 64 * (H1DIM * H1DIM);

#pragma unroll 1
    for (int oc_ch = 0; oc_ch < 4; ++oc_ch) {
        const int oc0 = ocHalf * 64 + oc_ch * 16;
        float acc[4][16];
#pragma unroll
        for (int a = 0; a < 4; ++a)
#pragma unroll
            for (int o = 0; o < 16; ++o) acc[a][o] = 0.f;

#pragma unroll 1
        for (int icc = 0; icc < 8; ++icc) {
            const int ic0 = icc * 8;
            __syncthreads();
            for (int e = tid; e < 8 * 18 * 66; e += 256) {
                int ic = e / (18 * 66);
                int rem = e - ic * (18 * 66);
                int r = rem / 66, c = rem - r * 66;
                int gr = R0 + r - 1, gc = C0 + c - 1;
                float v = 0.f;
                if (gr >= 0 && gr < H1DIM && gc >= 0 && gc < H1DIM)
                    v = h1b[((size_t)(ic0 + ic) * H1DIM + gr) * H1DIM + gc];
                hT[ic][r][c] = v;
            }
            __syncthreads();
#pragma unroll 1
            for (int i = 0; i < 8; ++i) {
#pragma unroll
                for (int ky = 0; ky < 3; ++ky) {
#pragma unroll
                    for (int kx = 0; kx < 3; ++kx) {
                        const float* __restrict__ wrow =
                            w2t + ((size_t)(ic0 + i) * 9 + ky * 3 + kx) * 128 + oc0;
                        float wv[16];
#pragma unroll
                        for (int o = 0; o < 16; ++o) wv[o] = wrow[o];
#pragma unroll
                        for (int a = 0; a < 4; ++a) {
                            float v = hT[i][ty + 4 * a + ky][tx + kx];
#pragma unroll
                            for (int o = 0; o < 16; ++o)
                                acc[a][o] = fmaf(v, wv[o], acc[a][o]);
                        }
                    }
                }
            }
        }
        // epilogue: BN+ReLU, mask to region A, wave-reduce, write partial
#pragma unroll
        for (int o = 0; o < 16; ++o) {
            int oc = oc0 + o;
            float sc = g2[oc] * rsqrtf(v2[oc] + 1e-5f);
            float bias = b2[oc], mm = m2[oc], bb = be2[oc];
            float s = 0.f;
#pragma unroll
            for (int a = 0; a < 4; ++a) {
                int R = R0 + ty + 4 * a, C = C0 + tx;
                if (R < ADIM && C < ADIM)
                    s += fmaxf((acc[a][o] + bias - mm) * sc + bb, 0.f);
            }
#pragma unroll
            for (int off = 32; off >= 1; off >>= 1) s += __shfl_xor(s, off, 64);
            if (tx == 0) {
                int tile = tile_r * 2 + tile_c;   // [0,16)
                partial[(((size_t)b * 16 + tile) * 4 + ty) * 128 + oc] = s;
            }
        }
    }
}

// ---- reduce partials + analytic constant regions -> mean[b][oc] ----
__global__ __launch_bounds__(128) void reduce_mean_kernel(
    const float* __restrict__ partial, const float* __restrict__ P,
    const float* __restrict__ b2, const float* __restrict__ g2,
    const float* __restrict__ be2, const float* __restrict__ m2,
    const float* __restrict__ v2, float* __restrict__ mean) {
    int b = blockIdx.x, oc = threadIdx.x;
    float s = 0.f;
    for (int j = 0; j < 64; ++j) s += partial[((size_t)b * 64 + j) * 128 + oc];

    float p[9];
#pragma unroll
    for (int t = 0; t < 9; ++t) p[t] = P[oc * 9 + t];

    float Sall = p[0] + p[1] + p[2] + p[3] + p[4] + p[5] + p[6] + p[7] + p[8];
    float Stop = p[3] + p[4] + p[5] + p[6] + p[7] + p[8];   // row 0 (ky=0 taps dropped)
    float Sbot = p[0] + p[1] + p[2] + p[3] + p[4] + p[5];   // row 223 (ky=2 dropped)
    float Sleft  = p[1] + p[2] + p[4] + p[5] + p[7] + p[8]; // col 0 (kx=0 dropped)
    float Sright = p[0] + p[1] + p[3] + p[4] + p[6] + p[7]; // col 223 (kx=2 dropped)
    float Ctr = p[3] + p[4] + p[6] + p[7];   // (0,223)
    float Cbl = p[1] + p[2] + p[4] + p[5];   // (223,0)
    float Cbr = p[0] + p[1] + p[3] + p[4];   // (223,223)

    float bias = b2[oc], mm = m2[oc], bb = be2[oc];
    float sc = g2[oc] * rsqrtf(v2[oc] + 1e-5f);
#define VALOF(S) fmaxf(((bias) + (S) - (mm)) * (sc) + (bb), 0.f)
    float cs = 36515.f * VALOF(Sall) + 109.f * VALOF(Stop) + 109.f * VALOF(Sleft)
             + 222.f * VALOF(Sbot) + 222.f * VALOF(Sright)
             + VALOF(Ctr) + VALOF(Cbl) + VALOF(Cbr);
#undef VALOF
    mean[b * 128 + oc] = (s + cs) * (1.f / (224.f * 224.f));
}

// ---- final linear: out[b][e] = sum_c mean[b][c]*wp[e][c] + bp[e] ----
__global__ __launch_bounds__(256) void final_linear_kernel(const float* __restrict__ mean,
                                                           const float* __restrict__ wp,
                                                           const float* __restrict__ bp,
                                                           float* __restrict__ out) {
    int b = blockIdx.x, e = threadIdx.x;
    __shared__ float mrow[128];
    if (threadIdx.x < 128) mrow[threadIdx.x] = mean[b * 128 + threadIdx.x];
    __syncthreads();
    float s = bp[e];
    for (int c = 0; c < 128; ++c) s = fmaf(mrow[c], wp[(size_t)e * 128 + c], s);
    out[(size_t)b * 256 + e] = s;
}

extern "C" void kernel_launch(void* const* d_in, const int* in_sizes, int n_in,
                              void* d_out, int out_size, void* d_ws, size_t ws_size,
                              hipStream_t stream) {
    const float* x   = (const float*)d_in[0];
    const float* w1  = (const float*)d_in[1];
    const float* b1  = (const float*)d_in[2];
    const float* g1  = (const float*)d_in[3];
    const float* be1 = (const float*)d_in[4];
    const float* m1  = (const float*)d_in[5];
    const float* v1  = (const float*)d_in[6];
    const float* w2  = (const float*)d_in[7];
    const float* b2  = (const float*)d_in[8];
    const float* g2  = (const float*)d_in[9];
    const float* be2 = (const float*)d_in[10];
    const float* m2  = (const float*)d_in[11];
    const float* v2  = (const float*)d_in[12];
    const float* wp  = (const float*)d_in[13];
    const float* bp  = (const float*)d_in[14];
    float* out = (float*)d_out;

    float* ws = (float*)d_ws;
    size_t off = 0;
    float* B    = ws + off; off += (size_t)NPIX * NPIX;        // 50176
    float* Bt   = ws + off; off += (size_t)NPIX * NPIX;        // 50176
    float* tmp1 = ws + off; off += (size_t)32 * NPIX * KEEP;   // 802816
    float* Xd   = ws + off; off += (size_t)32 * KEEP * KEEP;   // 401408
    float* c1   = ws + off; off += 64;
    float* P    = ws + off; off += 128 * 9;
    float* w2t  = ws + off; off += (size_t)64 * 9 * 128;       // 73728
    float* part = ws + off; off += (size_t)32 * 16 * 4 * 128;  // 262144
    float* mean = ws + off; off += 32 * 128;
    float* h1   = ws + off; off += (size_t)32 * 64 * H1DIM * H1DIM; // 27078400

    if (ws_size < off * sizeof(float)) return;  // workspace too small: fail visibly

    basis_kernel<<<dim3((NPIX * NPIX + 255) / 256), dim3(256), 0, stream>>>(B, Bt);
    dct_w_kernel<<<dim3(32 * NPIX), dim3(128), 0, stream>>>(x, Bt, tmp1);
    dct_h_kernel<<<dim3(KEEP, 32), dim3(128), 0, stream>>>(tmp1, B, Xd);
    prep_c1_kernel<<<dim3(1), dim3(64), 0, stream>>>(b1, g1, be1, m1, v1, c1);
    prep_P_kernel<<<dim3((128 * 9 + 255) / 256), dim3(256), 0, stream>>>(w2, c1, P);
    transpose_w2_kernel<<<dim3((128 * 64 * 9 + 255) / 256), dim3(256), 0, stream>>>(w2, w2t);
    conv1_kernel<<<dim3((H1DIM * H1DIM + 255) / 256, 64, 32), dim3(256), 0, stream>>>(
        Xd, w1, b1, g1, be1, m1, v1, h1);
    conv2_fused_kernel<<<dim3(4, 8, 32), dim3(256), 0, stream>>>(
        h1, w2t, b2, g2, be2, m2, v2, part);
    reduce_mean_kernel<<<dim3(32), dim3(128), 0, stream>>>(part, P, b2, g2, be2, m2, v2, mean);
    final_linear_kernel<<<dim3(32), dim3(256), 0, stream>>>(mean, wp, bp, out);
}

// Round 3
// 356.817 us; speedup vs baseline: 3.6155x; 3.6155x over previous
//
#include <hip/hip_runtime.h>
#include <math.h>

// ---------------------------------------------------------------------------
// DCTFrequencyEncoder: DCT2 -> mask(112x112) -> conv3x3(1->64)+BN+ReLU ->
// conv3x3(64->128)+BN+ReLU -> spatial mean -> linear(128->256)
//
// Mask sparsity: conv2 output is non-constant only on A=[0,114)^2; outside A
// it takes one of 8 analytic per-channel constants (validated in round 2).
// Round 3: conv2 is a bf16-MFMA implicit GEMM (9-tap shifted GEMM, K=64ic),
// h1 stored channel-last bf16. Everything else stays fp32.
// ---------------------------------------------------------------------------

#define NPIX 224
#define KEEP 112
#define H1DIM 115     // h1 computed on [0,115)^2
#define ADIM 114      // region A
#define ICS 72        // LDS ic-stride per pixel in shorts (144B, 16B-aligned, even bank spread)

typedef short bf16x8 __attribute__((ext_vector_type(8)));
typedef float f32x4  __attribute__((ext_vector_type(4)));

__device__ __forceinline__ unsigned short f2bf(float f) {
    unsigned int u = __float_as_uint(f);
    unsigned int r = (u + 0x7FFFu + ((u >> 16) & 1u)) >> 16;   // RNE
    return (unsigned short)r;
}

// ---- basis: B[k][n] = 2*cos(pi*k*(2n+1)/448), plus transpose ----
__global__ void basis_kernel(float* __restrict__ B, float* __restrict__ Bt) {
    int idx = blockIdx.x * 256 + threadIdx.x;
    if (idx >= NPIX * NPIX) return;
    int k = idx / NPIX, n = idx - k * NPIX;
    double ang = 3.14159265358979323846 * (double)k * (2.0 * n + 1.0) / (2.0 * NPIX);
    float v = (float)(2.0 * cos(ang));
    B[k * NPIX + n] = v;
    Bt[n * NPIX + k] = v;
}

// ---- DCT along W ----
__global__ __launch_bounds__(128) void dct_w_kernel(const float* __restrict__ x,
                                                    const float* __restrict__ Bt,
                                                    float* __restrict__ tmp1) {
    int bh = blockIdx.x;  // b*224 + h
    __shared__ float xr[NPIX];
    const float* row = x + (size_t)bh * NPIX;
    for (int i = threadIdx.x; i < NPIX; i += 128) xr[i] = row[i];
    __syncthreads();
    int kw = threadIdx.x;
    if (kw >= KEEP) return;
    float s = 0.f;
    for (int w = 0; w < NPIX; ++w) s = fmaf(xr[w], Bt[w * NPIX + kw], s);
    tmp1[(size_t)bh * KEEP + kw] = s;
}

// ---- DCT along H ----
__global__ __launch_bounds__(128) void dct_h_kernel(const float* __restrict__ tmp1,
                                                    const float* __restrict__ B,
                                                    float* __restrict__ Xd) {
    int kh = blockIdx.x;
    int b  = blockIdx.y;
    int kw = threadIdx.x;
    if (kw >= KEEP) return;
    const float* t = tmp1 + (size_t)b * NPIX * KEEP;
    const float* Bk = B + (size_t)kh * NPIX;
    float s = 0.f;
    for (int h = 0; h < NPIX; ++h) s = fmaf(t[h * KEEP + kw], Bk[h], s);
    Xd[((size_t)b * KEEP + kh) * KEEP + kw] = s;
}

// ---- c1[ic] = relu(bn1(b1)) ----
__global__ void prep_c1_kernel(const float* __restrict__ b1, const float* __restrict__ g1,
                               const float* __restrict__ be1, const float* __restrict__ m1,
                               const float* __restrict__ v1, float* __restrict__ c1) {
    int i = threadIdx.x;
    if (i < 64) {
        float sc = g1[i] * rsqrtf(v1[i] + 1e-5f);
        c1[i] = fmaxf((b1[i] - m1[i]) * sc + be1[i], 0.f);
    }
}

// ---- P[oc][tap] = sum_ic w2[oc,ic,tap] * c1[ic]  (fp32, analytic regions) ----
__global__ void prep_P_kernel(const float* __restrict__ w2, const float* __restrict__ c1,
                              float* __restrict__ P) {
    int idx = blockIdx.x * 256 + threadIdx.x;
    if (idx >= 128 * 9) return;
    int oc = idx / 9, tap = idx - oc * 9;
    float s = 0.f;
    for (int ic = 0; ic < 64; ++ic) s = fmaf(w2[((size_t)oc * 64 + ic) * 9 + tap], c1[ic], s);
    P[idx] = s;
}

// ---- w2b[tap][oc][ic] bf16 (B-operand layout: lane reads 8 consecutive ic) ----
__global__ void prep_w2b_kernel(const float* __restrict__ w2, unsigned short* __restrict__ w2b) {
    int idx = blockIdx.x * 256 + threadIdx.x;
    if (idx >= 128 * 64 * 9) return;
    int tap = idx % 9;
    int t2 = idx / 9;
    int ic = t2 & 63;
    int oc = t2 >> 6;
    w2b[((size_t)tap * 128 + oc) * 64 + ic] = f2bf(w2[idx]);
}

// ---- conv1 + BN + ReLU on [0,115)^2 -> channel-last bf16 h1c[b][r][c][64] ----
__global__ __launch_bounds__(256) void conv1_kernel(const float* __restrict__ Xd,
                                                    const float* __restrict__ w1,
                                                    const float* __restrict__ b1,
                                                    const float* __restrict__ g1,
                                                    const float* __restrict__ be1,
                                                    const float* __restrict__ m1,
                                                    const float* __restrict__ v1,
                                                    unsigned short* __restrict__ h1c) {
    __shared__ float wsm[64 * 9];
    __shared__ float wbm[64];
    int tid = threadIdx.x;
    if (tid < 64) {
        float sc = g1[tid] * rsqrtf(v1[tid] + 1e-5f);
        wbm[tid] = (b1[tid] - m1[tid]) * sc + be1[tid];
        for (int t = 0; t < 9; ++t) wsm[tid * 9 + t] = w1[tid * 9 + t] * sc;
    }
    __syncthreads();
    int b = blockIdx.y;
    int p = blockIdx.x * 256 + tid;
    if (p >= H1DIM * H1DIM) return;
    int r = p / H1DIM, c = p - r * H1DIM;
    const float* X = Xd + (size_t)b * KEEP * KEEP;
    float xv[9];
#pragma unroll
    for (int ky = 0; ky < 3; ++ky)
#pragma unroll
        for (int kx = 0; kx < 3; ++kx) {
            int rr = r + ky - 1, cc = c + kx - 1;
            xv[ky * 3 + kx] = ((unsigned)rr < (unsigned)KEEP && (unsigned)cc < (unsigned)KEEP)
                                  ? X[rr * KEEP + cc] : 0.f;
        }
    unsigned short* dst = h1c + ((size_t)b * (H1DIM * H1DIM) + p) * 64;
#pragma unroll 1
    for (int icg = 0; icg < 8; ++icg) {
        union { unsigned short us[8]; uint4 v; } u;
#pragma unroll
        for (int j = 0; j < 8; ++j) {
            int ic = icg * 8 + j;
            float s = wbm[ic];
#pragma unroll
            for (int t = 0; t < 9; ++t) s = fmaf(xv[t], wsm[ic * 9 + t], s);
            u.us[j] = f2bf(fmaxf(s, 0.f));
        }
        *reinterpret_cast<uint4*>(dst + icg * 8) = u.v;
    }
}

// ---- conv2 via bf16 MFMA: 9-tap shifted implicit GEMM, fused BN+ReLU+A-mask+sum ----
// grid (8 tc, 8 tr, 32 b), block 512 = 8 waves.
// Block tile: 16 rows x 16 cols x 128 oc. Wave w: mg=w&3 (rows 4mg..4mg+3), og=w>>2 (64 oc).
// MFMA 16x16x32: Mfrag = 16 px (one tile row), 4 Nfrags, kc in {0,1} (32 ic each).
__global__ __launch_bounds__(512, 2) void conv2_mfma_kernel(
    const unsigned short* __restrict__ h1c, const unsigned short* __restrict__ w2b,
    const float* __restrict__ b2, const float* __restrict__ g2,
    const float* __restrict__ be2, const float* __restrict__ m2,
    const float* __restrict__ v2, float* __restrict__ partial) {
    const int tc = blockIdx.x, tr = blockIdx.y, b = blockIdx.z;
    const int r0 = tr * 16, c0 = tc * 16;
    const int tid = threadIdx.x;
    const int lane = tid & 63, w = tid >> 6;
    const int mg = w & 3, og = w >> 2;
    const int l15 = lane & 15, h4 = lane >> 4;

    __shared__ unsigned short At[18 * 18 * ICS];   // 46656 B

    // stage A tile: rows r0-1..r0+16, cols c0-1..c0+16, 64 ic = 8 granules of 16B
    const unsigned short* __restrict__ h1b = h1c + (size_t)b * (H1DIM * H1DIM * 64);
    for (int gq = tid; gq < 18 * 18 * 8; gq += 512) {
        int pr = gq / (18 * 8);
        int rem = gq - pr * (18 * 8);
        int pc = rem >> 3;
        int gi = rem & 7;
        int gr = r0 + pr - 1, gc = c0 + pc - 1;
        uint4 v = make_uint4(0u, 0u, 0u, 0u);
        if ((unsigned)gr < (unsigned)H1DIM && (unsigned)gc < (unsigned)H1DIM)
            v = *reinterpret_cast<const uint4*>(h1b + ((size_t)(gr * H1DIM + gc)) * 64 + gi * 8);
        *reinterpret_cast<uint4*>(&At[(pr * 18 + pc) * ICS + gi * 8]) = v;
    }
    __syncthreads();

    f32x4 acc[4][4];
#pragma unroll
    for (int f = 0; f < 4; ++f)
#pragma unroll
        for (int n = 0; n < 4; ++n) acc[f][n] = (f32x4){0.f, 0.f, 0.f, 0.f};

    const int ocb = og * 64;
    // B element offset: tap*8192 + (ocb+16n+l15)*64 + kc*32 + h4*8
    const unsigned short* __restrict__ Bbase = w2b + (size_t)(ocb + l15) * 64 + h4 * 8;

    bf16x8 Bc0, Bc1, Bc2, Bc3, Bn0, Bn1, Bn2, Bn3;
    Bc0 = *reinterpret_cast<const bf16x8*>(Bbase + 0);
    Bc1 = *reinterpret_cast<const bf16x8*>(Bbase + 1024);
    Bc2 = *reinterpret_cast<const bf16x8*>(Bbase + 2048);
    Bc3 = *reinterpret_cast<const bf16x8*>(Bbase + 3072);

#pragma unroll
    for (int kc = 0; kc < 2; ++kc) {
#pragma unroll
        for (int t = 0; t < 9; ++t) {
            // prefetch next (tap,kc) B-frags
            int nk = kc, nt = t + 1;
            if (nt == 9) { nt = 0; nk = kc + 1; }
            if (nk < 2) {
                const unsigned short* nb = Bbase + (size_t)nt * 8192 + nk * 32;
                Bn0 = *reinterpret_cast<const bf16x8*>(nb + 0);
                Bn1 = *reinterpret_cast<const bf16x8*>(nb + 1024);
                Bn2 = *reinterpret_cast<const bf16x8*>(nb + 2048);
                Bn3 = *reinterpret_cast<const bf16x8*>(nb + 3072);
            }
            const int ky = t / 3, kx = t - ky * 3;
#pragma unroll
            for (int f = 0; f < 4; ++f) {
                const int ldsr = 4 * mg + f + ky;
                const int ldsc = l15 + kx;
                const bf16x8 a = *reinterpret_cast<const bf16x8*>(
                    &At[(ldsr * 18 + ldsc) * ICS + kc * 32 + h4 * 8]);
                acc[f][0] = __builtin_amdgcn_mfma_f32_16x16x32_bf16(a, Bc0, acc[f][0], 0, 0, 0);
                acc[f][1] = __builtin_amdgcn_mfma_f32_16x16x32_bf16(a, Bc1, acc[f][1], 0, 0, 0);
                acc[f][2] = __builtin_amdgcn_mfma_f32_16x16x32_bf16(a, Bc2, acc[f][2], 0, 0, 0);
                acc[f][3] = __builtin_amdgcn_mfma_f32_16x16x32_bf16(a, Bc3, acc[f][3], 0, 0, 0);
            }
            if (nk < 2) { Bc0 = Bn0; Bc1 = Bn1; Bc2 = Bn2; Bc3 = Bn3; }
        }
    }

    // epilogue: BN+ReLU, mask to region A, reduce over pixels, write per-(wave) partial
    const int tile = tr * 8 + tc;
    float* pslice = partial + (((size_t)b * 64 + tile) * 4 + mg) * 128;
#pragma unroll
    for (int n = 0; n < 4; ++n) {
        int oc = ocb + (n << 4) + l15;
        float sc = g2[oc] * rsqrtf(v2[oc] + 1e-5f);
        float bias = b2[oc] - m2[oc];
        float add = be2[oc];
        float s = 0.f;
#pragma unroll
        for (int f = 0; f < 4; ++f) {
            int row = r0 + 4 * mg + f;
            bool rok = row < ADIM;
#pragma unroll
            for (int i = 0; i < 4; ++i) {
                int col = c0 + (h4 << 2) + i;
                float v = fmaxf(fmaf(acc[f][n][i] + bias, sc, add), 0.f);
                s += (rok && col < ADIM) ? v : 0.f;
            }
        }
        s += __shfl_xor(s, 16);
        s += __shfl_xor(s, 32);
        if (lane < 16) pslice[oc] = s;
    }
}

// ---- reduce partials + analytic constant regions -> mean[b][oc] ----
__global__ __launch_bounds__(128) void reduce_mean_kernel(
    const float* __restrict__ partial, const float* __restrict__ P,
    const float* __restrict__ b2, const float* __restrict__ g2,
    const float* __restrict__ be2, const float* __restrict__ m2,
    const float* __restrict__ v2, float* __restrict__ mean) {
    int b = blockIdx.x, oc = threadIdx.x;
    float s = 0.f;
    for (int j = 0; j < 256; ++j) s += partial[((size_t)b * 256 + j) * 128 + oc];

    float p[9];
#pragma unroll
    for (int t = 0; t < 9; ++t) p[t] = P[oc * 9 + t];

    float Sall = p[0] + p[1] + p[2] + p[3] + p[4] + p[5] + p[6] + p[7] + p[8];
    float Stop = p[3] + p[4] + p[5] + p[6] + p[7] + p[8];
    float Sbot = p[0] + p[1] + p[2] + p[3] + p[4] + p[5];
    float Sleft  = p[1] + p[2] + p[4] + p[5] + p[7] + p[8];
    float Sright = p[0] + p[1] + p[3] + p[4] + p[6] + p[7];
    float Ctr = p[3] + p[4] + p[6] + p[7];
    float Cbl = p[1] + p[2] + p[4] + p[5];
    float Cbr = p[0] + p[1] + p[3] + p[4];

    float bias = b2[oc], mm = m2[oc], bb = be2[oc];
    float sc = g2[oc] * rsqrtf(v2[oc] + 1e-5f);
#define VALOF(S) fmaxf(((bias) + (S) - (mm)) * (sc) + (bb), 0.f)
    float cs = 36515.f * VALOF(Sall) + 109.f * VALOF(Stop) + 109.f * VALOF(Sleft)
             + 222.f * VALOF(Sbot) + 222.f * VALOF(Sright)
             + VALOF(Ctr) + VALOF(Cbl) + VALOF(Cbr);
#undef VALOF
    mean[b * 128 + oc] = (s + cs) * (1.f / (224.f * 224.f));
}

// ---- final linear ----
__global__ __launch_bounds__(256) void final_linear_kernel(const float* __restrict__ mean,
                                                           const float* __restrict__ wp,
                                                           const float* __restrict__ bp,
                                                           float* __restrict__ out) {
    int b = blockIdx.x, e = threadIdx.x;
    __shared__ float mrow[128];
    if (threadIdx.x < 128) mrow[threadIdx.x] = mean[b * 128 + threadIdx.x];
    __syncthreads();
    float s = bp[e];
    for (int c = 0; c < 128; ++c) s = fmaf(mrow[c], wp[(size_t)e * 128 + c], s);
    out[(size_t)b * 256 + e] = s;
}

extern "C" void kernel_launch(void* const* d_in, const int* in_sizes, int n_in,
                              void* d_out, int out_size, void* d_ws, size_t ws_size,
                              hipStream_t stream) {
    const float* x   = (const float*)d_in[0];
    const float* w1  = (const float*)d_in[1];
    const float* b1  = (const float*)d_in[2];
    const float* g1  = (const float*)d_in[3];
    const float* be1 = (const float*)d_in[4];
    const float* m1  = (const float*)d_in[5];
    const float* v1  = (const float*)d_in[6];
    const float* w2  = (const float*)d_in[7];
    const float* b2  = (const float*)d_in[8];
    const float* g2  = (const float*)d_in[9];
    const float* be2 = (const float*)d_in[10];
    const float* m2  = (const float*)d_in[11];
    const float* v2  = (const float*)d_in[12];
    const float* wp  = (const float*)d_in[13];
    const float* bp  = (const float*)d_in[14];
    float* out = (float*)d_out;

    float* ws = (float*)d_ws;
    size_t off = 0;
    float* B    = ws + off; off += (size_t)NPIX * NPIX;          // 50176
    float* Bt   = ws + off; off += (size_t)NPIX * NPIX;          // 50176
    float* tmp1 = ws + off; off += (size_t)32 * NPIX * KEEP;     // 802816
    float* Xd   = ws + off; off += (size_t)32 * KEEP * KEEP;     // 401408
    float* c1   = ws + off; off += 64;
    float* P    = ws + off; off += 128 * 9;
    unsigned short* w2b = (unsigned short*)(ws + off); off += (size_t)(128 * 64 * 9) / 2; // bf16
    float* part = ws + off; off += (size_t)32 * 64 * 4 * 128;    // 1048576
    float* mean = ws + off; off += 32 * 128;
    unsigned short* h1c = (unsigned short*)(ws + off);
    off += (size_t)32 * H1DIM * H1DIM * 64 / 2;                  // bf16: 13542400 floats

    if (ws_size < off * sizeof(float)) return;  // workspace too small: fail visibly

    basis_kernel<<<dim3((NPIX * NPIX + 255) / 256), dim3(256), 0, stream>>>(B, Bt);
    dct_w_kernel<<<dim3(32 * NPIX), dim3(128), 0, stream>>>(x, Bt, tmp1);
    dct_h_kernel<<<dim3(KEEP, 32), dim3(128), 0, stream>>>(tmp1, B, Xd);
    prep_c1_kernel<<<dim3(1), dim3(64), 0, stream>>>(b1, g1, be1, m1, v1, c1);
    prep_P_kernel<<<dim3((128 * 9 + 255) / 256), dim3(256), 0, stream>>>(w2, c1, P);
    prep_w2b_kernel<<<dim3((128 * 64 * 9 + 255) / 256), dim3(256), 0, stream>>>(w2, w2b);
    conv1_kernel<<<dim3((H1DIM * H1DIM + 255) / 256, 32), dim3(256), 0, stream>>>(
        Xd, w1, b1, g1, be1, m1, v1, h1c);
    conv2_mfma_kernel<<<dim3(8, 8, 32), dim3(512), 0, stream>>>(
        h1c, w2b, b2, g2, be2, m2, v2, part);
    reduce_mean_kernel<<<dim3(32), dim3(128), 0, stream>>>(part, P, b2, g2, be2, m2, v2, mean);
    final_linear_kernel<<<dim3(32), dim3(256), 0, stream>>>(mean, wp, bp, out);
}

// Round 4
// 338.403 us; speedup vs baseline: 3.8122x; 1.0544x over previous
//
#include <hip/hip_runtime.h>
#include <math.h>

// ---------------------------------------------------------------------------
// DCTFrequencyEncoder: DCT2 -> mask(112x112) -> conv3x3(1->64)+BN+ReLU ->
// conv3x3(64->128)+BN+ReLU -> spatial mean -> linear(128->256)
//
// Mask sparsity: conv2 output is non-constant only on A=[0,114)^2; outside A
// it takes one of 8 analytic per-channel constants (validated rounds 2-3).
// conv2 = bf16-MFMA implicit GEMM (verified mapping, round 3).
// Round 4: occupancy pin (512,4), ICS 80, row gating, DCT symmetry halving,
// scalar-weight conv1, fused prep.
// ---------------------------------------------------------------------------

#define NPIX 224
#define KEEP 112
#define H1DIM 115     // h1 computed on [0,115)^2
#define ADIM 114      // region A
#define ICS 80        // LDS ic-stride per pixel in shorts (160B: 4-way not 8-way)

typedef short bf16x8 __attribute__((ext_vector_type(8)));
typedef float f32x4  __attribute__((ext_vector_type(4)));

__device__ __forceinline__ unsigned short f2bf(float f) {
    unsigned int u = __float_as_uint(f);
    unsigned int r = (u + 0x7FFFu + ((u >> 16) & 1u)) >> 16;   // RNE
    return (unsigned short)r;
}

// ---- fused prep: [0,49) basis Bst[n][k]=2cos(pi k(2n+1)/448) (k,n<112);
//      [49] c1 + P + fused conv1 weights; [50,338) w2b bf16 transpose ----
__global__ __launch_bounds__(256) void prep_kernel(
    const float* __restrict__ w1, const float* __restrict__ b1,
    const float* __restrict__ g1, const float* __restrict__ be1,
    const float* __restrict__ m1, const float* __restrict__ v1,
    const float* __restrict__ w2,
    float* __restrict__ Bst, float* __restrict__ P,
    float* __restrict__ ws1, float* __restrict__ wb1,
    unsigned short* __restrict__ w2b) {
    int bx = blockIdx.x, tid = threadIdx.x;
    if (bx < 49) {
        int idx = bx * 256 + tid;
        if (idx < KEEP * KEEP) {
            int n = idx / KEEP, k = idx - n * KEEP;
            double ang = 3.14159265358979323846 * (double)k * (2.0 * n + 1.0) / (2.0 * NPIX);
            Bst[n * KEEP + k] = (float)(2.0 * cos(ang));
        }
    } else if (bx == 49) {
        __shared__ float c1s[64];
        if (tid < 64) {
            float sc = g1[tid] * rsqrtf(v1[tid] + 1e-5f);
            float c = fmaxf((b1[tid] - m1[tid]) * sc + be1[tid], 0.f);
            c1s[tid] = c;
            wb1[tid] = (b1[tid] - m1[tid]) * sc + be1[tid];
            for (int t = 0; t < 9; ++t) ws1[tid * 9 + t] = w1[tid * 9 + t] * sc;
        }
        __syncthreads();
        for (int idx = tid; idx < 128 * 9; idx += 256) {
            int oc = idx / 9, tap = idx - oc * 9;
            float s = 0.f;
            for (int ic = 0; ic < 64; ++ic)
                s = fmaf(w2[((size_t)oc * 64 + ic) * 9 + tap], c1s[ic], s);
            P[idx] = s;
        }
    } else {
        int idx = (bx - 50) * 256 + tid;
        if (idx < 128 * 64 * 9) {
            int tap = idx % 9;
            int t2 = idx / 9;
            int ic = t2 & 63;
            int oc = t2 >> 6;
            w2b[((size_t)tap * 128 + oc) * 64 + ic] = f2bf(w2[idx]);
        }
    }
}

// ---- DCT along W, symmetry-halved, 4 rows/block ----
__global__ __launch_bounds__(128) void dct_w_kernel(const float* __restrict__ x,
                                                    const float* __restrict__ Bst,
                                                    float* __restrict__ tmp1) {
    int blk = blockIdx.x;            // b*56 + rq ; covers rows 4rq..4rq+3 of image b
    int tid = threadIdx.x;
    __shared__ float eo[2][4][112];
    const float* rows = x + (size_t)blk * 4 * NPIX;
    for (int i = tid; i < 448; i += 128) {
        int r = i / 112, n = i - r * 112;
        float a = rows[r * NPIX + n], bv = rows[r * NPIX + 223 - n];
        eo[0][r][n] = a + bv;
        eo[1][r][n] = a - bv;
    }
    __syncthreads();
    int kw = tid;
    if (kw >= KEEP) return;
    const float* eop = &eo[kw & 1][0][0];
    float a0 = 0.f, a1 = 0.f, a2 = 0.f, a3 = 0.f;
    for (int n = 0; n < 112; ++n) {
        float bs = Bst[n * KEEP + kw];
        a0 = fmaf(eop[n], bs, a0);
        a1 = fmaf(eop[112 + n], bs, a1);
        a2 = fmaf(eop[224 + n], bs, a2);
        a3 = fmaf(eop[336 + n], bs, a3);
    }
    size_t base = (size_t)blk * 4 * KEEP + kw;
    tmp1[base] = a0; tmp1[base + 112] = a1; tmp1[base + 224] = a2; tmp1[base + 336] = a3;
}

// ---- DCT along H, symmetry-halved, 4 kh/block, basis via scalar loads ----
__global__ __launch_bounds__(128) void dct_h_kernel(const float* __restrict__ tmp1,
                                                    const float* __restrict__ Bst,
                                                    float* __restrict__ Xd) {
    int kq = blockIdx.x, b = blockIdx.y;
    int kw = threadIdx.x;
    if (kw >= KEEP) return;
    const float* t = tmp1 + (size_t)b * NPIX * KEEP + kw;
    const int kh0 = kq * 4;          // even
    float a0 = 0.f, a1 = 0.f, a2 = 0.f, a3 = 0.f;
    for (int h = 0; h < 112; ++h) {
        float lo = t[(size_t)h * KEEP];
        float hi = t[(size_t)(223 - h) * KEEP];
        float e = lo + hi, o = lo - hi;
        const float* bs = Bst + h * KEEP + kh0;   // wave-uniform -> s_load_dwordx4
        a0 = fmaf(e, bs[0], a0);
        a1 = fmaf(o, bs[1], a1);
        a2 = fmaf(e, bs[2], a2);
        a3 = fmaf(o, bs[3], a3);
    }
    float* X = Xd + ((size_t)b * KEEP + kh0) * KEEP + kw;
    X[0] = a0; X[112] = a1; X[224] = a2; X[336] = a3;
}

// ---- conv1 + BN + ReLU on [0,115)^2 -> channel-last bf16 h1c[b][r][c][64] ----
// weights pre-fused (ws1 = w1*sc, wb1 = bn bias), read via wave-uniform loads.
__global__ __launch_bounds__(256) void conv1_kernel(const float* __restrict__ Xd,
                                                    const float* __restrict__ ws1,
                                                    const float* __restrict__ wb1,
                                                    unsigned short* __restrict__ h1c) {
    int tid = threadIdx.x;
    int b = blockIdx.y;
    int p = blockIdx.x * 256 + tid;
    if (p >= H1DIM * H1DIM) return;
    int r = p / H1DIM, c = p - r * H1DIM;
    const float* X = Xd + (size_t)b * KEEP * KEEP;
    float xv[9];
#pragma unroll
    for (int ky = 0; ky < 3; ++ky)
#pragma unroll
        for (int kx = 0; kx < 3; ++kx) {
            int rr = r + ky - 1, cc = c + kx - 1;
            xv[ky * 3 + kx] = ((unsigned)rr < (unsigned)KEEP && (unsigned)cc < (unsigned)KEEP)
                                  ? X[rr * KEEP + cc] : 0.f;
        }
    unsigned short* dst = h1c + ((size_t)b * (H1DIM * H1DIM) + p) * 64;
#pragma unroll 1
    for (int icg = 0; icg < 8; ++icg) {
        union { unsigned short us[8]; uint4 v; } u;
#pragma unroll
        for (int j = 0; j < 8; ++j) {
            int ic = icg * 8 + j;
            float s = wb1[ic];
#pragma unroll
            for (int t = 0; t < 9; ++t) s = fmaf(xv[t], ws1[ic * 9 + t], s);
            u.us[j] = f2bf(fmaxf(s, 0.f));
        }
        *reinterpret_cast<uint4*>(dst + icg * 8) = u.v;
    }
}

// ---- conv2 via bf16 MFMA: 9-tap shifted implicit GEMM, fused BN+ReLU+A-mask+sum ----
// grid (8 tc, 8 tr, 32 b), block 512 = 8 waves, 2 blocks/CU pinned.
__global__ __launch_bounds__(512, 4) void conv2_mfma_kernel(
    const unsigned short* __restrict__ h1c, const unsigned short* __restrict__ w2b,
    const float* __restrict__ b2, const float* __restrict__ g2,
    const float* __restrict__ be2, const float* __restrict__ m2,
    const float* __restrict__ v2, float* __restrict__ partial) {
    const int tc = blockIdx.x, tr = blockIdx.y, b = blockIdx.z;
    const int r0 = tr * 16, c0 = tc * 16;
    const int tid = threadIdx.x;
    const int lane = tid & 63, w = tid >> 6;
    const int mg = w & 3, og = w >> 2;
    const int l15 = lane & 15, h4 = lane >> 4;

    __shared__ unsigned short At[18 * 18 * ICS];   // 51840 B

    // stage A tile: rows r0-1..r0+16, cols c0-1..c0+16, 64 ic = 8 granules of 16B
    const unsigned short* __restrict__ h1b = h1c + (size_t)b * (H1DIM * H1DIM * 64);
    for (int gq = tid; gq < 18 * 18 * 8; gq += 512) {
        int pr = gq / (18 * 8);
        int rem = gq - pr * (18 * 8);
        int pc = rem >> 3;
        int gi = rem & 7;
        int gr = r0 + pr - 1, gc = c0 + pc - 1;
        uint4 v = make_uint4(0u, 0u, 0u, 0u);
        if ((unsigned)gr < (unsigned)H1DIM && (unsigned)gc < (unsigned)H1DIM)
            v = *reinterpret_cast<const uint4*>(h1b + ((size_t)(gr * H1DIM + gc)) * 64 + gi * 8);
        *reinterpret_cast<uint4*>(&At[(pr * 18 + pc) * ICS + gi * 8]) = v;
    }
    __syncthreads();

    f32x4 acc[4][4];
#pragma unroll
    for (int f = 0; f < 4; ++f)
#pragma unroll
        for (int n = 0; n < 4; ++n) acc[f][n] = (f32x4){0.f, 0.f, 0.f, 0.f};

    const int ocb = og * 64;
    const unsigned short* __restrict__ Bbase = w2b + (size_t)(ocb + l15) * 64 + h4 * 8;

    const bool wave_active = (r0 + 4 * mg) < ADIM;   // wave-uniform row gate
    if (wave_active) {
        bf16x8 Bc0, Bc1, Bc2, Bc3, Bn0, Bn1, Bn2, Bn3;
        Bc0 = *reinterpret_cast<const bf16x8*>(Bbase + 0);
        Bc1 = *reinterpret_cast<const bf16x8*>(Bbase + 1024);
        Bc2 = *reinterpret_cast<const bf16x8*>(Bbase + 2048);
        Bc3 = *reinterpret_cast<const bf16x8*>(Bbase + 3072);

#pragma unroll
        for (int kc = 0; kc < 2; ++kc) {
#pragma unroll
            for (int t = 0; t < 9; ++t) {
                int nk = kc, nt = t + 1;
                if (nt == 9) { nt = 0; nk = kc + 1; }
                if (nk < 2) {
                    const unsigned short* nb = Bbase + (size_t)nt * 8192 + nk * 32;
                    Bn0 = *reinterpret_cast<const bf16x8*>(nb + 0);
                    Bn1 = *reinterpret_cast<const bf16x8*>(nb + 1024);
                    Bn2 = *reinterpret_cast<const bf16x8*>(nb + 2048);
                    Bn3 = *reinterpret_cast<const bf16x8*>(nb + 3072);
                }
                const int ky = t / 3, kx = t - ky * 3;
#pragma unroll
                for (int f = 0; f < 4; ++f) {
                    if (r0 + 4 * mg + f < ADIM) {    // per-row gate (wave-uniform)
                        const int ldsr = 4 * mg + f + ky;
                        const int ldsc = l15 + kx;
                        const bf16x8 a = *reinterpret_cast<const bf16x8*>(
                            &At[(ldsr * 18 + ldsc) * ICS + kc * 32 + h4 * 8]);
                        acc[f][0] = __builtin_amdgcn_mfma_f32_16x16x32_bf16(a, Bc0, acc[f][0], 0, 0, 0);
                        acc[f][1] = __builtin_amdgcn_mfma_f32_16x16x32_bf16(a, Bc1, acc[f][1], 0, 0, 0);
                        acc[f][2] = __builtin_amdgcn_mfma_f32_16x16x32_bf16(a, Bc2, acc[f][2], 0, 0, 0);
                        acc[f][3] = __builtin_amdgcn_mfma_f32_16x16x32_bf16(a, Bc3, acc[f][3], 0, 0, 0);
                    }
                }
                if (nk < 2) { Bc0 = Bn0; Bc1 = Bn1; Bc2 = Bn2; Bc3 = Bn3; }
            }
        }
    }

    // epilogue: BN+ReLU, mask to region A, reduce over pixels, write partials
    const int tile = tr * 8 + tc;
    float* pslice = partial + (((size_t)b * 64 + tile) * 4 + mg) * 128;
#pragma unroll
    for (int n = 0; n < 4; ++n) {
        int oc = ocb + (n << 4) + l15;
        float sc = g2[oc] * rsqrtf(v2[oc] + 1e-5f);
        float bias = b2[oc] - m2[oc];
        float add = be2[oc];
        float s = 0.f;
#pragma unroll
        for (int f = 0; f < 4; ++f) {
            int row = r0 + 4 * mg + f;
            bool rok = row < ADIM;
#pragma unroll
            for (int i = 0; i < 4; ++i) {
                int col = c0 + (h4 << 2) + i;
                float v = fmaxf(fmaf(acc[f][n][i] + bias, sc, add), 0.f);
                s += (rok && col < ADIM) ? v : 0.f;
            }
        }
        s += __shfl_xor(s, 16);
        s += __shfl_xor(s, 32);
        if (lane < 16) pslice[oc] = s;
    }
}

// ---- reduce partials + analytic constant regions -> mean[b][oc] ----
__global__ __launch_bounds__(128) void reduce_mean_kernel(
    const float* __restrict__ partial, const float* __restrict__ P,
    const float* __restrict__ b2, const float* __restrict__ g2,
    const float* __restrict__ be2, const float* __restrict__ m2,
    const float* __restrict__ v2, float* __restrict__ mean) {
    int b = blockIdx.x, oc = threadIdx.x;
    float s = 0.f;
    for (int j = 0; j < 256; ++j) s += partial[((size_t)b * 256 + j) * 128 + oc];

    float p[9];
#pragma unroll
    for (int t = 0; t < 9; ++t) p[t] = P[oc * 9 + t];

    float Sall = p[0] + p[1] + p[2] + p[3] + p[4] + p[5] + p[6] + p[7] + p[8];
    float Stop = p[3] + p[4] + p[5] + p[6] + p[7] + p[8];
    float Sbot = p[0] + p[1] + p[2] + p[3] + p[4] + p[5];
    float Sleft  = p[1] + p[2] + p[4] + p[5] + p[7] + p[8];
    float Sright = p[0] + p[1] + p[3] + p[4] + p[6] + p[7];
    float Ctr = p[3] + p[4] + p[6] + p[7];
    float Cbl = p[1] + p[2] + p[4] + p[5];
    float Cbr = p[0] + p[1] + p[3] + p[4];

    float bias = b2[oc], mm = m2[oc], bb = be2[oc];
    float sc = g2[oc] * rsqrtf(v2[oc] + 1e-5f);
#define VALOF(S) fmaxf(((bias) + (S) - (mm)) * (sc) + (bb), 0.f)
    float cs = 36515.f * VALOF(Sall) + 109.f * VALOF(Stop) + 109.f * VALOF(Sleft)
             + 222.f * VALOF(Sbot) + 222.f * VALOF(Sright)
             + VALOF(Ctr) + VALOF(Cbl) + VALOF(Cbr);
#undef VALOF
    mean[b * 128 + oc] = (s + cs) * (1.f / (224.f * 224.f));
}

// ---- final linear ----
__global__ __launch_bounds__(256) void final_linear_kernel(const float* __restrict__ mean,
                                                           const float* __restrict__ wp,
                                                           const float* __restrict__ bp,
                                                           float* __restrict__ out) {
    int b = blockIdx.x, e = threadIdx.x;
    __shared__ float mrow[128];
    if (threadIdx.x < 128) mrow[threadIdx.x] = mean[b * 128 + threadIdx.x];
    __syncthreads();
    float s = bp[e];
    for (int c = 0; c < 128; ++c) s = fmaf(mrow[c], wp[(size_t)e * 128 + c], s);
    out[(size_t)b * 256 + e] = s;
}

extern "C" void kernel_launch(void* const* d_in, const int* in_sizes, int n_in,
                              void* d_out, int out_size, void* d_ws, size_t ws_size,
                              hipStream_t stream) {
    const float* x   = (const float*)d_in[0];
    const float* w1  = (const float*)d_in[1];
    const float* b1  = (const float*)d_in[2];
    const float* g1  = (const float*)d_in[3];
    const float* be1 = (const float*)d_in[4];
    const float* m1  = (const float*)d_in[5];
    const float* v1  = (const float*)d_in[6];
    const float* w2  = (const float*)d_in[7];
    const float* b2  = (const float*)d_in[8];
    const float* g2  = (const float*)d_in[9];
    const float* be2 = (const float*)d_in[10];
    const float* m2  = (const float*)d_in[11];
    const float* v2  = (const float*)d_in[12];
    const float* wp  = (const float*)d_in[13];
    const float* bp  = (const float*)d_in[14];
    float* out = (float*)d_out;

    float* ws = (float*)d_ws;
    size_t off = 0;
    float* Bst  = ws + off; off += (size_t)KEEP * KEEP;          // 12544
    float* tmp1 = ws + off; off += (size_t)32 * NPIX * KEEP;     // 802816
    float* Xd   = ws + off; off += (size_t)32 * KEEP * KEEP;     // 401408
    float* P    = ws + off; off += 128 * 9;
    float* ws1  = ws + off; off += 64 * 9;
    float* wb1  = ws + off; off += 64;
    unsigned short* w2b = (unsigned short*)(ws + off); off += (size_t)(128 * 64 * 9) / 2;
    float* part = ws + off; off += (size_t)32 * 64 * 4 * 128;    // 1048576
    float* mean = ws + off; off += 32 * 128;
    unsigned short* h1c = (unsigned short*)(ws + off);
    off += (size_t)32 * H1DIM * H1DIM * 64 / 2;                  // bf16

    if (ws_size < off * sizeof(float)) return;  // workspace too small: fail visibly

    prep_kernel<<<dim3(338), dim3(256), 0, stream>>>(w1, b1, g1, be1, m1, v1, w2,
                                                     Bst, P, ws1, wb1, w2b);
    dct_w_kernel<<<dim3(32 * 56), dim3(128), 0, stream>>>(x, Bst, tmp1);
    dct_h_kernel<<<dim3(28, 32), dim3(128), 0, stream>>>(tmp1, Bst, Xd);
    conv1_kernel<<<dim3((H1DIM * H1DIM + 255) / 256, 32), dim3(256), 0, stream>>>(
        Xd, ws1, wb1, h1c);
    conv2_mfma_kernel<<<dim3(8, 8, 32), dim3(512), 0, stream>>>(
        h1c, w2b, b2, g2, be2, m2, v2, part);
    reduce_mean_kernel<<<dim3(32), dim3(128), 0, stream>>>(part, P, b2, g2, be2, m2, v2, mean);
    final_linear_kernel<<<dim3(32), dim3(256), 0, stream>>>(mean, wp, bp, out);
}

// Round 5
// 244.480 us; speedup vs baseline: 5.2768x; 1.3842x over previous
//
#include <hip/hip_runtime.h>
#include <math.h>

// ---------------------------------------------------------------------------
// DCTFrequencyEncoder: DCT2 -> mask(112x112) -> conv3x3(1->64)+BN+ReLU ->
// conv3x3(64->128)+BN+ReLU -> spatial mean -> linear(128->256)
//
// Mask sparsity: conv2 output non-constant only on A=[0,114)^2; outside A it
// takes one of 8 analytic per-channel constants (validated rounds 2-4).
// Round 5: conv1 rewritten (px,icg)-per-thread w/ coalesced stores (was the
// hidden 175us); conv2 B-pipeline via compile-time alternating buffers
// (kills per-tap register-rotate vmcnt(0) drain); dct_h 4-way split.
// ---------------------------------------------------------------------------

#define NPIX 224
#define KEEP 112
#define H1DIM 115     // h1 computed on [0,115)^2
#define ADIM 114      // region A
#define ICS 80        // LDS ic-stride per pixel in shorts (160B: measured 0 conflicts)

typedef short bf16x8 __attribute__((ext_vector_type(8)));
typedef float f32x4  __attribute__((ext_vector_type(4)));

__device__ __forceinline__ unsigned short f2bf(float f) {
    unsigned int u = __float_as_uint(f);
    unsigned int r = (u + 0x7FFFu + ((u >> 16) & 1u)) >> 16;   // RNE
    return (unsigned short)r;
}

// ---- fused prep: [0,49) basis Bst[n][k]=2cos(pi k(2n+1)/448) (k,n<112);
//      [49] c1 + P + fused conv1 weights; [50,338) w2b bf16 transpose ----
__global__ __launch_bounds__(256) void prep_kernel(
    const float* __restrict__ w1, const float* __restrict__ b1,
    const float* __restrict__ g1, const float* __restrict__ be1,
    const float* __restrict__ m1, const float* __restrict__ v1,
    const float* __restrict__ w2,
    float* __restrict__ Bst, float* __restrict__ P,
    float* __restrict__ ws1, float* __restrict__ wb1,
    unsigned short* __restrict__ w2b) {
    int bx = blockIdx.x, tid = threadIdx.x;
    if (bx < 49) {
        int idx = bx * 256 + tid;
        if (idx < KEEP * KEEP) {
            int n = idx / KEEP, k = idx - n * KEEP;
            double ang = 3.14159265358979323846 * (double)k * (2.0 * n + 1.0) / (2.0 * NPIX);
            Bst[n * KEEP + k] = (float)(2.0 * cos(ang));
        }
    } else if (bx == 49) {
        __shared__ float c1s[64];
        if (tid < 64) {
            float sc = g1[tid] * rsqrtf(v1[tid] + 1e-5f);
            float c = fmaxf((b1[tid] - m1[tid]) * sc + be1[tid], 0.f);
            c1s[tid] = c;
            wb1[tid] = (b1[tid] - m1[tid]) * sc + be1[tid];
            for (int t = 0; t < 9; ++t) ws1[tid * 9 + t] = w1[tid * 9 + t] * sc;
        }
        __syncthreads();
        for (int idx = tid; idx < 128 * 9; idx += 256) {
            int oc = idx / 9, tap = idx - oc * 9;
            float s = 0.f;
            for (int ic = 0; ic < 64; ++ic)
                s = fmaf(w2[((size_t)oc * 64 + ic) * 9 + tap], c1s[ic], s);
            P[idx] = s;
        }
    } else {
        int idx = (bx - 50) * 256 + tid;
        if (idx < 128 * 64 * 9) {
            int tap = idx % 9;
            int t2 = idx / 9;
            int ic = t2 & 63;
            int oc = t2 >> 6;
            w2b[((size_t)tap * 128 + oc) * 64 + ic] = f2bf(w2[idx]);
        }
    }
}

// ---- DCT along W, symmetry-halved, 4 rows/block ----
__global__ __launch_bounds__(128) void dct_w_kernel(const float* __restrict__ x,
                                                    const float* __restrict__ Bst,
                                                    float* __restrict__ tmp1) {
    int blk = blockIdx.x;            // b*56 + rq ; covers rows 4rq..4rq+3 of image b
    int tid = threadIdx.x;
    __shared__ float eo[2][4][112];
    const float* rows = x + (size_t)blk * 4 * NPIX;
    for (int i = tid; i < 448; i += 128) {
        int r = i / 112, n = i - r * 112;
        float a = rows[r * NPIX + n], bv = rows[r * NPIX + 223 - n];
        eo[0][r][n] = a + bv;
        eo[1][r][n] = a - bv;
    }
    __syncthreads();
    int kw = tid;
    if (kw >= KEEP) return;
    const float* eop = &eo[kw & 1][0][0];
    float a0 = 0.f, a1 = 0.f, a2 = 0.f, a3 = 0.f;
    for (int n = 0; n < 112; ++n) {
        float bs = Bst[n * KEEP + kw];
        a0 = fmaf(eop[n], bs, a0);
        a1 = fmaf(eop[112 + n], bs, a1);
        a2 = fmaf(eop[224 + n], bs, a2);
        a3 = fmaf(eop[336 + n], bs, a3);
    }
    size_t base = (size_t)blk * 4 * KEEP + kw;
    tmp1[base] = a0; tmp1[base + 112] = a1; tmp1[base + 224] = a2; tmp1[base + 336] = a3;
}

// ---- DCT along H, symmetry-halved, 4 kh/block, 4-way h-split (512 thr) ----
__global__ __launch_bounds__(512) void dct_h_kernel(const float* __restrict__ tmp1,
                                                    const float* __restrict__ Bst,
                                                    float* __restrict__ Xd) {
    int kq = blockIdx.x, b = blockIdx.y;
    int tid = threadIdx.x;
    int kw = tid & 127, sub = tid >> 7;   // sub 0..3
    __shared__ float ps[3][4][112];
    const int kh0 = kq * 4;
    float a0 = 0.f, a1 = 0.f, a2 = 0.f, a3 = 0.f;
    if (kw < KEEP) {
        const float* t = tmp1 + (size_t)b * NPIX * KEEP + kw;
        for (int h = sub * 28; h < sub * 28 + 28; ++h) {
            float lo = t[(size_t)h * KEEP];
            float hi = t[(size_t)(223 - h) * KEEP];
            float e = lo + hi, o = lo - hi;
            const float* bs = Bst + h * KEEP + kh0;   // wave-uniform -> s_load
            a0 = fmaf(e, bs[0], a0);
            a1 = fmaf(o, bs[1], a1);
            a2 = fmaf(e, bs[2], a2);
            a3 = fmaf(o, bs[3], a3);
        }
        if (sub) {
            ps[sub - 1][0][kw] = a0; ps[sub - 1][1][kw] = a1;
            ps[sub - 1][2][kw] = a2; ps[sub - 1][3][kw] = a3;
        }
    }
    __syncthreads();
    if (sub == 0 && kw < KEEP) {
        a0 += ps[0][0][kw] + ps[1][0][kw] + ps[2][0][kw];
        a1 += ps[0][1][kw] + ps[1][1][kw] + ps[2][1][kw];
        a2 += ps[0][2][kw] + ps[1][2][kw] + ps[2][2][kw];
        a3 += ps[0][3][kw] + ps[1][3][kw] + ps[2][3][kw];
        float* X = Xd + ((size_t)b * KEEP + kh0) * KEEP + kw;
        X[0] = a0; X[112] = a1; X[224] = a2; X[336] = a3;
    }
}

// ---- conv1 + BN + ReLU on [0,115)^2 -> channel-last bf16 h1c[b][r][c][64] ----
// thread = (px, icg): 72 FMA each, coalesced 16B-contiguous stores (1KB/wave).
// grid (4 cblk, 115 rows, 32 b), block 256 = 32 px x 8 icg.
__global__ __launch_bounds__(256) void conv1_kernel(const float* __restrict__ Xd,
                                                    const float* __restrict__ ws1,
                                                    const float* __restrict__ wb1,
                                                    unsigned short* __restrict__ h1c) {
    const int r = blockIdx.y, b = blockIdx.z;
    const int c0 = blockIdx.x * 32;
    const int tid = threadIdx.x;
    __shared__ float xs[3][36];       // rows r-1..r+1, cols c0-1..c0+32
    __shared__ float wsm[8][73];      // [icg][(ic&7)*9+t], +pad for bank spread
    __shared__ float wbs[64];
    const float* X = Xd + (size_t)b * KEEP * KEEP;
    for (int i = tid; i < 102; i += 256) {
        int dr = i / 34, dc = i - dr * 34;
        int rr = r - 1 + dr, cc = c0 - 1 + dc;
        xs[dr][dc] = ((unsigned)rr < (unsigned)KEEP && (unsigned)cc < (unsigned)KEEP)
                         ? X[rr * KEEP + cc] : 0.f;
    }
    for (int i = tid; i < 576; i += 256) {
        int ic = i / 9, t = i - ic * 9;
        wsm[ic >> 3][(ic & 7) * 9 + t] = ws1[i];
    }
    if (tid < 64) wbs[tid] = wb1[tid];
    __syncthreads();

    const int px = tid >> 3, icg = tid & 7;
    const int c = c0 + px;
    float xv[9];
#pragma unroll
    for (int ky = 0; ky < 3; ++ky)
#pragma unroll
        for (int kx = 0; kx < 3; ++kx) xv[ky * 3 + kx] = xs[ky][px + kx];

    union { unsigned short us[8]; uint4 v; } u;
#pragma unroll
    for (int j = 0; j < 8; ++j) {
        float s = wbs[icg * 8 + j];
#pragma unroll
        for (int t = 0; t < 9; ++t) s = fmaf(xv[t], wsm[icg][j * 9 + t], s);
        u.us[j] = f2bf(fmaxf(s, 0.f));
    }
    if (c < H1DIM) {
        unsigned short* dst = h1c + (((size_t)b * H1DIM + r) * H1DIM + c) * 64 + icg * 8;
        *reinterpret_cast<uint4*>(dst) = u.v;
    }
}

// ---- conv2 via bf16 MFMA: 9-tap shifted implicit GEMM, fused BN+ReLU+A-mask+sum ----
// grid (8 tc, 8 tr, 32 b), block 512 = 8 waves.
// Full-unroll 18-step K-loop, compile-time alternating B buffers (no reg rotate).
__global__ __launch_bounds__(512, 4) void conv2_mfma_kernel(
    const unsigned short* __restrict__ h1c, const unsigned short* __restrict__ w2b,
    const float* __restrict__ b2, const float* __restrict__ g2,
    const float* __restrict__ be2, const float* __restrict__ m2,
    const float* __restrict__ v2, float* __restrict__ partial) {
    const int tc = blockIdx.x, tr = blockIdx.y, b = blockIdx.z;
    const int r0 = tr * 16, c0 = tc * 16;
    const int tid = threadIdx.x;
    const int lane = tid & 63, w = tid >> 6;
    const int mg = w & 3, og = w >> 2;
    const int l15 = lane & 15, h4 = lane >> 4;

    __shared__ unsigned short At[18 * 18 * ICS];   // 51840 B

    const unsigned short* __restrict__ h1b = h1c + (size_t)b * (H1DIM * H1DIM * 64);
    for (int gq = tid; gq < 18 * 18 * 8; gq += 512) {
        int pr = gq / (18 * 8);
        int rem = gq - pr * (18 * 8);
        int pc = rem >> 3;
        int gi = rem & 7;
        int gr = r0 + pr - 1, gc = c0 + pc - 1;
        uint4 v = make_uint4(0u, 0u, 0u, 0u);
        if ((unsigned)gr < (unsigned)H1DIM && (unsigned)gc < (unsigned)H1DIM)
            v = *reinterpret_cast<const uint4*>(h1b + ((size_t)(gr * H1DIM + gc)) * 64 + gi * 8);
        *reinterpret_cast<uint4*>(&At[(pr * 18 + pc) * ICS + gi * 8]) = v;
    }
    __syncthreads();

    f32x4 acc[4][4];
#pragma unroll
    for (int f = 0; f < 4; ++f)
#pragma unroll
        for (int n = 0; n < 4; ++n) acc[f][n] = (f32x4){0.f, 0.f, 0.f, 0.f};

    const int ocb = og * 64;
    const unsigned short* __restrict__ Bbase = w2b + (size_t)(ocb + l15) * 64 + h4 * 8;

    const bool wave_active = (r0 + 4 * mg) < ADIM;   // wave-uniform row gate
    if (wave_active) {
        bf16x8 Bf[2][4];
        // prologue: load step 0 (kc=0, tap=0)
        Bf[0][0] = *reinterpret_cast<const bf16x8*>(Bbase + 0);
        Bf[0][1] = *reinterpret_cast<const bf16x8*>(Bbase + 1024);
        Bf[0][2] = *reinterpret_cast<const bf16x8*>(Bbase + 2048);
        Bf[0][3] = *reinterpret_cast<const bf16x8*>(Bbase + 3072);

#pragma unroll
        for (int s = 0; s < 18; ++s) {
            const int kc = s / 9, t = s - 9 * kc;
            // issue loads for step s+1 (alternating buffer; indices compile-time)
            if (s + 1 < 18) {
                const int nk = (s + 1) / 9, nt = (s + 1) - 9 * nk;
                const unsigned short* nb = Bbase + (size_t)nt * 8192 + nk * 32;
                Bf[(s + 1) & 1][0] = *reinterpret_cast<const bf16x8*>(nb + 0);
                Bf[(s + 1) & 1][1] = *reinterpret_cast<const bf16x8*>(nb + 1024);
                Bf[(s + 1) & 1][2] = *reinterpret_cast<const bf16x8*>(nb + 2048);
                Bf[(s + 1) & 1][3] = *reinterpret_cast<const bf16x8*>(nb + 3072);
            }
            const int ky = t / 3, kx = t - ky * 3;
#pragma unroll
            for (int f = 0; f < 4; ++f) {
                if (r0 + 4 * mg + f < ADIM) {        // wave-uniform
                    const int ldsr = 4 * mg + f + ky;
                    const int ldsc = l15 + kx;
                    const bf16x8 a = *reinterpret_cast<const bf16x8*>(
                        &At[(ldsr * 18 + ldsc) * ICS + kc * 32 + h4 * 8]);
                    acc[f][0] = __builtin_amdgcn_mfma_f32_16x16x32_bf16(a, Bf[s & 1][0], acc[f][0], 0, 0, 0);
                    acc[f][1] = __builtin_amdgcn_mfma_f32_16x16x32_bf16(a, Bf[s & 1][1], acc[f][1], 0, 0, 0);
                    acc[f][2] = __builtin_amdgcn_mfma_f32_16x16x32_bf16(a, Bf[s & 1][2], acc[f][2], 0, 0, 0);
                    acc[f][3] = __builtin_amdgcn_mfma_f32_16x16x32_bf16(a, Bf[s & 1][3], acc[f][3], 0, 0, 0);
                }
            }
        }
    }

    // epilogue: BN+ReLU, mask to region A, reduce over pixels, write partials
    const int tile = tr * 8 + tc;
    float* pslice = partial + (((size_t)b * 64 + tile) * 4 + mg) * 128;
#pragma unroll
    for (int n = 0; n < 4; ++n) {
        int oc = ocb + (n << 4) + l15;
        float sc = g2[oc] * rsqrtf(v2[oc] + 1e-5f);
        float bias = b2[oc] - m2[oc];
        float add = be2[oc];
        float s = 0.f;
#pragma unroll
        for (int f = 0; f < 4; ++f) {
            int row = r0 + 4 * mg + f;
            bool rok = row < ADIM;
#pragma unroll
            for (int i = 0; i < 4; ++i) {
                int col = c0 + (h4 << 2) + i;
                float v = fmaxf(fmaf(acc[f][n][i] + bias, sc, add), 0.f);
                s += (rok && col < ADIM) ? v : 0.f;
            }
        }
        s += __shfl_xor(s, 16);
        s += __shfl_xor(s, 32);
        if (lane < 16) pslice[oc] = s;
    }
}

// ---- reduce partials + analytic constant regions -> mean[b][oc] ----
__global__ __launch_bounds__(128) void reduce_mean_kernel(
    const float* __restrict__ partial, const float* __restrict__ P,
    const float* __restrict__ b2, const float* __restrict__ g2,
    const float* __restrict__ be2, const float* __restrict__ m2,
    const float* __restrict__ v2, float* __restrict__ mean) {
    int b = blockIdx.x, oc = threadIdx.x;
    float s = 0.f;
    for (int j = 0; j < 256; ++j) s += partial[((size_t)b * 256 + j) * 128 + oc];

    float p[9];
#pragma unroll
    for (int t = 0; t < 9; ++t) p[t] = P[oc * 9 + t];

    float Sall = p[0] + p[1] + p[2] + p[3] + p[4] + p[5] + p[6] + p[7] + p[8];
    float Stop = p[3] + p[4] + p[5] + p[6] + p[7] + p[8];
    float Sbot = p[0] + p[1] + p[2] + p[3] + p[4] + p[5];
    float Sleft  = p[1] + p[2] + p[4] + p[5] + p[7] + p[8];
    float Sright = p[0] + p[1] + p[3] + p[4] + p[6] + p[7];
    float Ctr = p[3] + p[4] + p[6] + p[7];
    float Cbl = p[1] + p[2] + p[4] + p[5];
    float Cbr = p[0] + p[1] + p[3] + p[4];

    float bias = b2[oc], mm = m2[oc], bb = be2[oc];
    float sc = g2[oc] * rsqrtf(v2[oc] + 1e-5f);
#define VALOF(S) fmaxf(((bias) + (S) - (mm)) * (sc) + (bb), 0.f)
    float cs = 36515.f * VALOF(Sall) + 109.f * VALOF(Stop) + 109.f * VALOF(Sleft)
             + 222.f * VALOF(Sbot) + 222.f * VALOF(Sright)
             + VALOF(Ctr) + VALOF(Cbl) + VALOF(Cbr);
#undef VALOF
    mean[b * 128 + oc] = (s + cs) * (1.f / (224.f * 224.f));
}

// ---- final linear ----
__global__ __launch_bounds__(256) void final_linear_kernel(const float* __restrict__ mean,
                                                           const float* __restrict__ wp,
                                                           const float* __restrict__ bp,
                                                           float* __restrict__ out) {
    int b = blockIdx.x, e = threadIdx.x;
    __shared__ float mrow[128];
    if (threadIdx.x < 128) mrow[threadIdx.x] = mean[b * 128 + threadIdx.x];
    __syncthreads();
    float s = bp[e];
    for (int c = 0; c < 128; ++c) s = fmaf(mrow[c], wp[(size_t)e * 128 + c], s);
    out[(size_t)b * 256 + e] = s;
}

extern "C" void kernel_launch(void* const* d_in, const int* in_sizes, int n_in,
                              void* d_out, int out_size, void* d_ws, size_t ws_size,
                              hipStream_t stream) {
    const float* x   = (const float*)d_in[0];
    const float* w1  = (const float*)d_in[1];
    const float* b1  = (const float*)d_in[2];
    const float* g1  = (const float*)d_in[3];
    const float* be1 = (const float*)d_in[4];
    const float* m1  = (const float*)d_in[5];
    const float* v1  = (const float*)d_in[6];
    const float* w2  = (const float*)d_in[7];
    const float* b2  = (const float*)d_in[8];
    const float* g2  = (const float*)d_in[9];
    const float* be2 = (const float*)d_in[10];
    const float* m2  = (const float*)d_in[11];
    const float* v2  = (const float*)d_in[12];
    const float* wp  = (const float*)d_in[13];
    const float* bp  = (const float*)d_in[14];
    float* out = (float*)d_out;

    float* ws = (float*)d_ws;
    size_t off = 0;
    float* Bst  = ws + off; off += (size_t)KEEP * KEEP;          // 12544
    float* tmp1 = ws + off; off += (size_t)32 * NPIX * KEEP;     // 802816
    float* Xd   = ws + off; off += (size_t)32 * KEEP * KEEP;     // 401408
    float* P    = ws + off; off += 128 * 9;
    float* ws1  = ws + off; off += 64 * 9;
    float* wb1  = ws + off; off += 64;
    unsigned short* w2b = (unsigned short*)(ws + off); off += (size_t)(128 * 64 * 9) / 2;
    float* part = ws + off; off += (size_t)32 * 64 * 4 * 128;    // 1048576
    float* mean = ws + off; off += 32 * 128;
    unsigned short* h1c = (unsigned short*)(ws + off);
    off += (size_t)32 * H1DIM * H1DIM * 64 / 2;                  // bf16

    if (ws_size < off * sizeof(float)) return;  // workspace too small: fail visibly

    prep_kernel<<<dim3(338), dim3(256), 0, stream>>>(w1, b1, g1, be1, m1, v1, w2,
                                                     Bst, P, ws1, wb1, w2b);
    dct_w_kernel<<<dim3(32 * 56), dim3(128), 0, stream>>>(x, Bst, tmp1);
    dct_h_kernel<<<dim3(28, 32), dim3(512), 0, stream>>>(tmp1, Bst, Xd);
    conv1_kernel<<<dim3(4, H1DIM, 32), dim3(256), 0, stream>>>(Xd, ws1, wb1, h1c);
    conv2_mfma_kernel<<<dim3(8, 8, 32), dim3(512), 0, stream>>>(
        h1c, w2b, b2, g2, be2, m2, v2, part);
    reduce_mean_kernel<<<dim3(32), dim3(128), 0, stream>>>(part, P, b2, g2, be2, m2, v2, mean);
    final_linear_kernel<<<dim3(32), dim3(256), 0, stream>>>(mean, wp, bp, out);
}

// Round 6
// 166.998 us; speedup vs baseline: 7.7251x; 1.4640x over previous
//
#include <hip/hip_runtime.h>
#include <math.h>

// ---------------------------------------------------------------------------
// DCTFrequencyEncoder: DCT2 -> mask(112x112) -> conv3x3(1->64)+BN+ReLU ->
// conv3x3(64->128)+BN+ReLU -> spatial mean -> linear(128->256)
//
// Mask sparsity: conv2 output non-constant only on A=[0,114)^2; outside A it
// takes one of 8 analytic per-channel constants (validated rounds 2-5).
// Round 6: conv2 B-loads were L2 line-BW bound (16 half-used lines/instr).
// Fix: lane-contiguous pre-packed B fragments (w2f) + f=8/n=2 wave shape
// (half the B loads) + ICS=64 XOR-swizzled A tile (41.5KB LDS).
// ---------------------------------------------------------------------------

#define NPIX 224
#define KEEP 112
#define H1DIM 115     // h1 computed on [0,115)^2
#define ADIM 114      // region A

typedef short bf16x8 __attribute__((ext_vector_type(8)));
typedef float f32x4  __attribute__((ext_vector_type(4)));

__device__ __forceinline__ unsigned short f2bf(float f) {
    unsigned int u = __float_as_uint(f);
    unsigned int r = (u + 0x7FFFu + ((u >> 16) & 1u)) >> 16;   // RNE
    return (unsigned short)r;
}

// ---- fused prep: [0,49) basis Bst[n][k]=2cos(pi k(2n+1)/448) (k,n<112);
//      [49] c1 + P + fused conv1 weights; [50,86) w2f fragment packing ----
// w2f frag layout: frag_id = (tap*2+kc)*8 + g16; element = lane(0..63);
// value = bf16x8 of w2[oc = g16*16 + (lane&15)][ic = kc*32+(lane>>4)*8 ..+8][tap]
__global__ __launch_bounds__(256) void prep_kernel(
    const float* __restrict__ w1, const float* __restrict__ b1,
    const float* __restrict__ g1, const float* __restrict__ be1,
    const float* __restrict__ m1, const float* __restrict__ v1,
    const float* __restrict__ w2,
    float* __restrict__ Bst, float* __restrict__ P,
    float* __restrict__ ws1, float* __restrict__ wb1,
    uint4* __restrict__ w2f) {
    int bx = blockIdx.x, tid = threadIdx.x;
    if (bx < 49) {
        int idx = bx * 256 + tid;
        if (idx < KEEP * KEEP) {
            int n = idx / KEEP, k = idx - n * KEEP;
            double ang = 3.14159265358979323846 * (double)k * (2.0 * n + 1.0) / (2.0 * NPIX);
            Bst[n * KEEP + k] = (float)(2.0 * cos(ang));
        }
    } else if (bx == 49) {
        __shared__ float c1s[64];
        if (tid < 64) {
            float sc = g1[tid] * rsqrtf(v1[tid] + 1e-5f);
            float c = fmaxf((b1[tid] - m1[tid]) * sc + be1[tid], 0.f);
            c1s[tid] = c;
            wb1[tid] = (b1[tid] - m1[tid]) * sc + be1[tid];
            for (int t = 0; t < 9; ++t) ws1[tid * 9 + t] = w1[tid * 9 + t] * sc;
        }
        __syncthreads();
        for (int idx = tid; idx < 128 * 9; idx += 256) {
            int oc = idx / 9, tap = idx - oc * 9;
            float s = 0.f;
            for (int ic = 0; ic < 64; ++ic)
                s = fmaf(w2[((size_t)oc * 64 + ic) * 9 + tap], c1s[ic], s);
            P[idx] = s;
        }
    } else {
        int j = (bx - 50) * 256 + tid;   // uint4 index, total 9*2*8*64 = 9216
        if (j < 9216) {
            int t = j >> 10;             // /1024
            int r = j & 1023;
            int kc = (r >> 9) & 1;
            int g16 = (r >> 6) & 7;
            int lane = r & 63;
            int oc = g16 * 16 + (lane & 15);
            int ic0 = kc * 32 + (lane >> 4) * 8;
            union { unsigned short us[8]; uint4 v; } u;
#pragma unroll
            for (int q = 0; q < 8; ++q)
                u.us[q] = f2bf(w2[((size_t)oc * 64 + ic0 + q) * 9 + t]);
            w2f[j] = u.v;
        }
    }
}

// ---- DCT along W, symmetry-halved, 4 rows/block ----
__global__ __launch_bounds__(128) void dct_w_kernel(const float* __restrict__ x,
                                                    const float* __restrict__ Bst,
                                                    float* __restrict__ tmp1) {
    int blk = blockIdx.x;            // b*56 + rq ; covers rows 4rq..4rq+3 of image b
    int tid = threadIdx.x;
    __shared__ float eo[2][4][112];
    const float* rows = x + (size_t)blk * 4 * NPIX;
    for (int i = tid; i < 448; i += 128) {
        int r = i / 112, n = i - r * 112;
        float a = rows[r * NPIX + n], bv = rows[r * NPIX + 223 - n];
        eo[0][r][n] = a + bv;
        eo[1][r][n] = a - bv;
    }
    __syncthreads();
    int kw = tid;
    if (kw >= KEEP) return;
    const float* eop = &eo[kw & 1][0][0];
    float a0 = 0.f, a1 = 0.f, a2 = 0.f, a3 = 0.f;
    for (int n = 0; n < 112; ++n) {
        float bs = Bst[n * KEEP + kw];
        a0 = fmaf(eop[n], bs, a0);
        a1 = fmaf(eop[112 + n], bs, a1);
        a2 = fmaf(eop[224 + n], bs, a2);
        a3 = fmaf(eop[336 + n], bs, a3);
    }
    size_t base = (size_t)blk * 4 * KEEP + kw;
    tmp1[base] = a0; tmp1[base + 112] = a1; tmp1[base + 224] = a2; tmp1[base + 336] = a3;
}

// ---- DCT along H, symmetry-halved, 4 kh/block, 4-way h-split (512 thr) ----
__global__ __launch_bounds__(512) void dct_h_kernel(const float* __restrict__ tmp1,
                                                    const float* __restrict__ Bst,
                                                    float* __restrict__ Xd) {
    int kq = blockIdx.x, b = blockIdx.y;
    int tid = threadIdx.x;
    int kw = tid & 127, sub = tid >> 7;   // sub 0..3
    __shared__ float ps[3][4][112];
    const int kh0 = kq * 4;
    float a0 = 0.f, a1 = 0.f, a2 = 0.f, a3 = 0.f;
    if (kw < KEEP) {
        const float* t = tmp1 + (size_t)b * NPIX * KEEP + kw;
        for (int h = sub * 28; h < sub * 28 + 28; ++h) {
            float lo = t[(size_t)h * KEEP];
            float hi = t[(size_t)(223 - h) * KEEP];
            float e = lo + hi, o = lo - hi;
            const float* bs = Bst + h * KEEP + kh0;   // wave-uniform -> s_load
            a0 = fmaf(e, bs[0], a0);
            a1 = fmaf(o, bs[1], a1);
            a2 = fmaf(e, bs[2], a2);
            a3 = fmaf(o, bs[3], a3);
        }
        if (sub) {
            ps[sub - 1][0][kw] = a0; ps[sub - 1][1][kw] = a1;
            ps[sub - 1][2][kw] = a2; ps[sub - 1][3][kw] = a3;
        }
    }
    __syncthreads();
    if (sub == 0 && kw < KEEP) {
        a0 += ps[0][0][kw] + ps[1][0][kw] + ps[2][0][kw];
        a1 += ps[0][1][kw] + ps[1][1][kw] + ps[2][1][kw];
        a2 += ps[0][2][kw] + ps[1][2][kw] + ps[2][2][kw];
        a3 += ps[0][3][kw] + ps[1][3][kw] + ps[2][3][kw];
        float* X = Xd + ((size_t)b * KEEP + kh0) * KEEP + kw;
        X[0] = a0; X[112] = a1; X[224] = a2; X[336] = a3;
    }
}

// ---- conv1 + BN + ReLU on [0,115)^2 -> channel-last bf16 h1c[b][r][c][64] ----
__global__ __launch_bounds__(256) void conv1_kernel(const float* __restrict__ Xd,
                                                    const float* __restrict__ ws1,
                                                    const float* __restrict__ wb1,
                                                    unsigned short* __restrict__ h1c) {
    const int r = blockIdx.y, b = blockIdx.z;
    const int c0 = blockIdx.x * 32;
    const int tid = threadIdx.x;
    __shared__ float xs[3][36];       // rows r-1..r+1, cols c0-1..c0+32
    __shared__ float wsm[8][73];      // [icg][(ic&7)*9+t], +pad for bank spread
    __shared__ float wbs[64];
    const float* X = Xd + (size_t)b * KEEP * KEEP;
    for (int i = tid; i < 102; i += 256) {
        int dr = i / 34, dc = i - dr * 34;
        int rr = r - 1 + dr, cc = c0 - 1 + dc;
        xs[dr][dc] = ((unsigned)rr < (unsigned)KEEP && (unsigned)cc < (unsigned)KEEP)
                         ? X[rr * KEEP + cc] : 0.f;
    }
    for (int i = tid; i < 576; i += 256) {
        int ic = i / 9, t = i - ic * 9;
        wsm[ic >> 3][(ic & 7) * 9 + t] = ws1[i];
    }
    if (tid < 64) wbs[tid] = wb1[tid];
    __syncthreads();

    const int px = tid >> 3, icg = tid & 7;
    const int c = c0 + px;
    float xv[9];
#pragma unroll
    for (int ky = 0; ky < 3; ++ky)
#pragma unroll
        for (int kx = 0; kx < 3; ++kx) xv[ky * 3 + kx] = xs[ky][px + kx];

    union { unsigned short us[8]; uint4 v; } u;
#pragma unroll
    for (int j = 0; j < 8; ++j) {
        float s = wbs[icg * 8 + j];
#pragma unroll
        for (int t = 0; t < 9; ++t) s = fmaf(xv[t], wsm[icg][j * 9 + t], s);
        u.us[j] = f2bf(fmaxf(s, 0.f));
    }
    if (c < H1DIM) {
        unsigned short* dst = h1c + (((size_t)b * H1DIM + r) * H1DIM + c) * 64 + icg * 8;
        *reinterpret_cast<uint4*>(dst) = u.v;
    }
}

// ---- conv2 via bf16 MFMA: 9-tap shifted implicit GEMM, fused BN+ReLU+A-mask+sum ----
// grid (8 tc, 8 tr, 32 b), block 512 = 8 waves = 2 mg x 4 og.
// Wave: 8 M-frags (rows 8mg..8mg+7) x 2 N-frags (oc og*32..og*32+31).
// B fragments pre-packed lane-contiguous in w2f: 1 wave load = 1KB contiguous.
__global__ __launch_bounds__(512, 4) void conv2_mfma_kernel(
    const unsigned short* __restrict__ h1c, const uint4* __restrict__ w2f,
    const float* __restrict__ b2, const float* __restrict__ g2,
    const float* __restrict__ be2, const float* __restrict__ m2,
    const float* __restrict__ v2, float* __restrict__ partial) {
    const int tc = blockIdx.x, tr = blockIdx.y, b = blockIdx.z;
    const int r0 = tr * 16, c0 = tc * 16;
    const int tid = threadIdx.x;
    const int lane = tid & 63, w = tid >> 6;
    const int mg = w & 1, og = w >> 1;
    const int l15 = lane & 15, h4 = lane >> 4;

    __shared__ unsigned short At[324 * 64];   // 41472 B, XOR-swizzled

    // stage A tile: rows r0-1..r0+16, cols c0-1..c0+16, 64 ic = 8 granules of 16B
    const unsigned short* __restrict__ h1b = h1c + (size_t)b * (H1DIM * H1DIM * 64);
    for (int e = tid; e < 2592; e += 512) {
        int px = e >> 3, gi = e & 7;
        int pr = px / 18, pc = px - pr * 18;
        int gr = r0 + pr - 1, gc = c0 + pc - 1;
        uint4 v = make_uint4(0u, 0u, 0u, 0u);
        if ((unsigned)gr < (unsigned)H1DIM && (unsigned)gc < (unsigned)H1DIM)
            v = *reinterpret_cast<const uint4*>(h1b + ((size_t)(gr * H1DIM + gc)) * 64 + gi * 8);
        *reinterpret_cast<uint4*>(&At[px * 64 + ((gi * 8) ^ ((px & 7) << 3))]) = v;
    }
    __syncthreads();

    f32x4 acc[8][2];
#pragma unroll
    for (int f = 0; f < 8; ++f)
#pragma unroll
        for (int n = 0; n < 2; ++n) acc[f][n] = (f32x4){0.f, 0.f, 0.f, 0.f};

    const bool wave_active = (r0 + 8 * mg) < ADIM;   // wave-uniform row gate
    if (wave_active) {
        bf16x8 Bf[2][2];
#define LOADB(buf, t, kc)                                                               \
    Bf[buf][0] = *reinterpret_cast<const bf16x8*>(                                      \
        w2f + (((t) * 2 + (kc)) * 8 + og * 2 + 0) * 64 + lane);                         \
    Bf[buf][1] = *reinterpret_cast<const bf16x8*>(                                      \
        w2f + (((t) * 2 + (kc)) * 8 + og * 2 + 1) * 64 + lane);
        LOADB(0, 0, 0);
#pragma unroll
        for (int s = 0; s < 18; ++s) {
            const int kc = s / 9, t = s - 9 * kc;
            if (s + 1 < 18) {
                const int nk = (s + 1) / 9, nt = (s + 1) - 9 * nk;
                LOADB((s + 1) & 1, nt, nk);
            }
            const int ky = t / 3, kx = t - 3 * ky;
#pragma unroll
            for (int f = 0; f < 8; ++f) {
                if (r0 + 8 * mg + f < ADIM) {        // wave-uniform per-row gate
                    const int px = (8 * mg + f + ky) * 18 + l15 + kx;
                    const bf16x8 a = *reinterpret_cast<const bf16x8*>(
                        &At[px * 64 + ((kc * 32 + h4 * 8) ^ ((px & 7) << 3))]);
                    acc[f][0] = __builtin_amdgcn_mfma_f32_16x16x32_bf16(a, Bf[s & 1][0], acc[f][0], 0, 0, 0);
                    acc[f][1] = __builtin_amdgcn_mfma_f32_16x16x32_bf16(a, Bf[s & 1][1], acc[f][1], 0, 0, 0);
                }
            }
        }
#undef LOADB
    }

    // epilogue: BN+ReLU, mask to region A, reduce over pixels, write partials
    const int tile = tr * 8 + tc;
    float* pslice = partial + (((size_t)b * 64 + tile) * 2 + mg) * 128;
#pragma unroll
    for (int n = 0; n < 2; ++n) {
        int oc = og * 32 + n * 16 + l15;
        float sc = g2[oc] * rsqrtf(v2[oc] + 1e-5f);
        float bias = b2[oc] - m2[oc];
        float add = be2[oc];
        float s = 0.f;
#pragma unroll
        for (int f = 0; f < 8; ++f) {
            int row = r0 + 8 * mg + f;
            bool rok = row < ADIM;
#pragma unroll
            for (int i = 0; i < 4; ++i) {
                int col = c0 + (h4 << 2) + i;
                float v = fmaxf(fmaf(acc[f][n][i] + bias, sc, add), 0.f);
                s += (rok && col < ADIM) ? v : 0.f;
            }
        }
        s += __shfl_xor(s, 16);
        s += __shfl_xor(s, 32);
        if (lane < 16) pslice[oc] = s;
    }
}

// ---- reduce partials + analytic constant regions -> mean[b][oc] ----
__global__ __launch_bounds__(128) void reduce_mean_kernel(
    const float* __restrict__ partial, const float* __restrict__ P,
    const float* __restrict__ b2, const float* __restrict__ g2,
    const float* __restrict__ be2, const float* __restrict__ m2,
    const float* __restrict__ v2, float* __restrict__ mean) {
    int b = blockIdx.x, oc = threadIdx.x;
    float s = 0.f;
    for (int j = 0; j < 128; ++j) s += partial[((size_t)b * 128 + j) * 128 + oc];

    float p[9];
#pragma unroll
    for (int t = 0; t < 9; ++t) p[t] = P[oc * 9 + t];

    float Sall = p[0] + p[1] + p[2] + p[3] + p[4] + p[5] + p[6] + p[7] + p[8];
    float Stop = p[3] + p[4] + p[5] + p[6] + p[7] + p[8];
    float Sbot = p[0] + p[1] + p[2] + p[3] + p[4] + p[5];
    float Sleft  = p[1] + p[2] + p[4] + p[5] + p[7] + p[8];
    float Sright = p[0] + p[1] + p[3] + p[4] + p[6] + p[7];
    float Ctr = p[3] + p[4] + p[6] + p[7];
    float Cbl = p[1] + p[2] + p[4] + p[5];
    float Cbr = p[0] + p[1] + p[3] + p[4];

    float bias = b2[oc], mm = m2[oc], bb = be2[oc];
    float sc = g2[oc] * rsqrtf(v2[oc] + 1e-5f);
#define VALOF(S) fmaxf(((bias) + (S) - (mm)) * (sc) + (bb), 0.f)
    float cs = 36515.f * VALOF(Sall) + 109.f * VALOF(Stop) + 109.f * VALOF(Sleft)
             + 222.f * VALOF(Sbot) + 222.f * VALOF(Sright)
             + VALOF(Ctr) + VALOF(Cbl) + VALOF(Cbr);
#undef VALOF
    mean[b * 128 + oc] = (s + cs) * (1.f / (224.f * 224.f));
}

// ---- final linear ----
__global__ __launch_bounds__(256) void final_linear_kernel(const float* __restrict__ mean,
                                                           const float* __restrict__ wp,
                                                           const float* __restrict__ bp,
                                                           float* __restrict__ out) {
    int b = blockIdx.x, e = threadIdx.x;
    __shared__ float mrow[128];
    if (threadIdx.x < 128) mrow[threadIdx.x] = mean[b * 128 + threadIdx.x];
    __syncthreads();
    float s = bp[e];
    for (int c = 0; c < 128; ++c) s = fmaf(mrow[c], wp[(size_t)e * 128 + c], s);
    out[(size_t)b * 256 + e] = s;
}

extern "C" void kernel_launch(void* const* d_in, const int* in_sizes, int n_in,
                              void* d_out, int out_size, void* d_ws, size_t ws_size,
                              hipStream_t stream) {
    const float* x   = (const float*)d_in[0];
    const float* w1  = (const float*)d_in[1];
    const float* b1  = (const float*)d_in[2];
    const float* g1  = (const float*)d_in[3];
    const float* be1 = (const float*)d_in[4];
    const float* m1  = (const float*)d_in[5];
    const float* v1  = (const float*)d_in[6];
    const float* w2  = (const float*)d_in[7];
    const float* b2  = (const float*)d_in[8];
    const float* g2  = (const float*)d_in[9];
    const float* be2 = (const float*)d_in[10];
    const float* m2  = (const float*)d_in[11];
    const float* v2  = (const float*)d_in[12];
    const float* wp  = (const float*)d_in[13];
    const float* bp  = (const float*)d_in[14];
    float* out = (float*)d_out;

    float* ws = (float*)d_ws;
    size_t off = 0;
    float* Bst  = ws + off; off += (size_t)KEEP * KEEP;          // 12544
    float* tmp1 = ws + off; off += (size_t)32 * NPIX * KEEP;     // 802816
    float* Xd   = ws + off; off += (size_t)32 * KEEP * KEEP;     // 401408
    float* P    = ws + off; off += 128 * 9;
    float* ws1  = ws + off; off += 64 * 9;
    float* wb1  = ws + off; off += 64;
    uint4* w2f  = (uint4*)(ws + off); off += (size_t)9216 * 4;   // 9216 uint4
    float* part = ws + off; off += (size_t)32 * 128 * 128;       // 524288
    float* mean = ws + off; off += 32 * 128;
    unsigned short* h1c = (unsigned short*)(ws + off);
    off += (size_t)32 * H1DIM * H1DIM * 64 / 2;                  // bf16

    if (ws_size < off * sizeof(float)) return;  // workspace too small: fail visibly

    prep_kernel<<<dim3(86), dim3(256), 0, stream>>>(w1, b1, g1, be1, m1, v1, w2,
                                                    Bst, P, ws1, wb1, w2f);
    dct_w_kernel<<<dim3(32 * 56), dim3(128), 0, stream>>>(x, Bst, tmp1);
    dct_h_kernel<<<dim3(28, 32), dim3(512), 0, stream>>>(tmp1, Bst, Xd);
    conv1_kernel<<<dim3(4, H1DIM, 32), dim3(256), 0, stream>>>(Xd, ws1, wb1, h1c);
    conv2_mfma_kernel<<<dim3(8, 8, 32), dim3(512), 0, stream>>>(
        h1c, w2f, b2, g2, be2, m2, v2, part);
    reduce_mean_kernel<<<dim3(32), dim3(128), 0, stream>>>(part, P, b2, g2, be2, m2, v2, mean);
    final_linear_kernel<<<dim3(32), dim3(256), 0, stream>>>(mean, wp, bp, out);
}

// Round 7
// 154.477 us; speedup vs baseline: 8.3512x; 1.0811x over previous
//
#include <hip/hip_runtime.h>
#include <math.h>

// ---------------------------------------------------------------------------
// DCTFrequencyEncoder: DCT2 -> mask(112x112) -> conv3x3(1->64)+BN+ReLU ->
// conv3x3(64->128)+BN+ReLU -> spatial mean -> linear(128->256)
//
// Mask sparsity: conv2 output non-constant only on A=[0,114)^2; outside A it
// takes one of 8 analytic per-channel constants (validated rounds 2-6).
// Round 7: conv2 f=4/n=4 (1:4 ds_read:MFMA, halves LDS-pipe load) keeping
// packed-B; prep P-section split over 5 blocks (was 1-block latency chain);
// reduce_mean re-gridded (32,8)x256; final_linear float4.
// ---------------------------------------------------------------------------

#define NPIX 224
#define KEEP 112
#define H1DIM 115     // h1 computed on [0,115)^2
#define ADIM 114      // region A

typedef short bf16x8 __attribute__((ext_vector_type(8)));
typedef float f32x4  __attribute__((ext_vector_type(4)));

__device__ __forceinline__ unsigned short f2bf(float f) {
    unsigned int u = __float_as_uint(f);
    unsigned int r = (u + 0x7FFFu + ((u >> 16) & 1u)) >> 16;   // RNE
    return (unsigned short)r;
}

// ---- fused prep ----
// [0,49): basis Bst[n][k]=2cos(pi k(2n+1)/448) (k,n<112)
// [49,54): P[oc][tap] = sum_ic w2*c1 (5 blocks, c1 recomputed per block)
// [54]: fused conv1 weights ws1/wb1
// [55,91): w2f fragment packing:
//   frag_id=(tap*2+kc)*8+g16, elem=lane; bf16x8 of
//   w2[oc=g16*16+(lane&15)][ic=kc*32+(lane>>4)*8..+8][tap]
__global__ __launch_bounds__(256) void prep_kernel(
    const float* __restrict__ w1, const float* __restrict__ b1,
    const float* __restrict__ g1, const float* __restrict__ be1,
    const float* __restrict__ m1, const float* __restrict__ v1,
    const float* __restrict__ w2,
    float* __restrict__ Bst, float* __restrict__ P,
    float* __restrict__ ws1, float* __restrict__ wb1,
    uint4* __restrict__ w2f) {
    int bx = blockIdx.x, tid = threadIdx.x;
    if (bx < 49) {
        int idx = bx * 256 + tid;
        if (idx < KEEP * KEEP) {
            int n = idx / KEEP, k = idx - n * KEEP;
            double ang = 3.14159265358979323846 * (double)k * (2.0 * n + 1.0) / (2.0 * NPIX);
            Bst[n * KEEP + k] = (float)(2.0 * cos(ang));
        }
    } else if (bx < 54) {
        __shared__ float c1s[64];
        if (tid < 64) {
            float sc = g1[tid] * rsqrtf(v1[tid] + 1e-5f);
            c1s[tid] = fmaxf((b1[tid] - m1[tid]) * sc + be1[tid], 0.f);
        }
        __syncthreads();
        int idx = (bx - 49) * 256 + tid;
        if (idx < 128 * 9) {
            int oc = idx / 9, tap = idx - oc * 9;
            float s = 0.f;
            for (int ic = 0; ic < 64; ++ic)
                s = fmaf(w2[((size_t)oc * 64 + ic) * 9 + tap], c1s[ic], s);
            P[idx] = s;
        }
    } else if (bx == 54) {
        if (tid < 64) {
            float sc = g1[tid] * rsqrtf(v1[tid] + 1e-5f);
            wb1[tid] = (b1[tid] - m1[tid]) * sc + be1[tid];
            for (int t = 0; t < 9; ++t) ws1[tid * 9 + t] = w1[tid * 9 + t] * sc;
        }
    } else {
        int j = (bx - 55) * 256 + tid;   // uint4 index, total 9*2*8*64 = 9216
        if (j < 9216) {
            int t = j >> 10;             // /1024
            int r = j & 1023;
            int kc = (r >> 9) & 1;
            int g16 = (r >> 6) & 7;
            int lane = r & 63;
            int oc = g16 * 16 + (lane & 15);
            int ic0 = kc * 32 + (lane >> 4) * 8;
            union { unsigned short us[8]; uint4 v; } u;
#pragma unroll
            for (int q = 0; q < 8; ++q)
                u.us[q] = f2bf(w2[((size_t)oc * 64 + ic0 + q) * 9 + t]);
            w2f[j] = u.v;
        }
    }
}

// ---- DCT along W, symmetry-halved, 4 rows/block ----
__global__ __launch_bounds__(128) void dct_w_kernel(const float* __restrict__ x,
                                                    const float* __restrict__ Bst,
                                                    float* __restrict__ tmp1) {
    int blk = blockIdx.x;            // b*56 + rq ; covers rows 4rq..4rq+3 of image b
    int tid = threadIdx.x;
    __shared__ float eo[2][4][112];
    const float* rows = x + (size_t)blk * 4 * NPIX;
    for (int i = tid; i < 448; i += 128) {
        int r = i / 112, n = i - r * 112;
        float a = rows[r * NPIX + n], bv = rows[r * NPIX + 223 - n];
        eo[0][r][n] = a + bv;
        eo[1][r][n] = a - bv;
    }
    __syncthreads();
    int kw = tid;
    if (kw >= KEEP) return;
    const float* eop = &eo[kw & 1][0][0];
    float a0 = 0.f, a1 = 0.f, a2 = 0.f, a3 = 0.f;
    for (int n = 0; n < 112; ++n) {
        float bs = Bst[n * KEEP + kw];
        a0 = fmaf(eop[n], bs, a0);
        a1 = fmaf(eop[112 + n], bs, a1);
        a2 = fmaf(eop[224 + n], bs, a2);
        a3 = fmaf(eop[336 + n], bs, a3);
    }
    size_t base = (size_t)blk * 4 * KEEP + kw;
    tmp1[base] = a0; tmp1[base + 112] = a1; tmp1[base + 224] = a2; tmp1[base + 336] = a3;
}

// ---- DCT along H, symmetry-halved, 4 kh/block, 4-way h-split (512 thr) ----
__global__ __launch_bounds__(512) void dct_h_kernel(const float* __restrict__ tmp1,
                                                    const float* __restrict__ Bst,
                                                    float* __restrict__ Xd) {
    int kq = blockIdx.x, b = blockIdx.y;
    int tid = threadIdx.x;
    int kw = tid & 127, sub = tid >> 7;   // sub 0..3
    __shared__ float ps[3][4][112];
    const int kh0 = kq * 4;
    float a0 = 0.f, a1 = 0.f, a2 = 0.f, a3 = 0.f;
    if (kw < KEEP) {
        const float* t = tmp1 + (size_t)b * NPIX * KEEP + kw;
        for (int h = sub * 28; h < sub * 28 + 28; ++h) {
            float lo = t[(size_t)h * KEEP];
            float hi = t[(size_t)(223 - h) * KEEP];
            float e = lo + hi, o = lo - hi;
            const float* bs = Bst + h * KEEP + kh0;   // wave-uniform -> s_load
            a0 = fmaf(e, bs[0], a0);
            a1 = fmaf(o, bs[1], a1);
            a2 = fmaf(e, bs[2], a2);
            a3 = fmaf(o, bs[3], a3);
        }
        if (sub) {
            ps[sub - 1][0][kw] = a0; ps[sub - 1][1][kw] = a1;
            ps[sub - 1][2][kw] = a2; ps[sub - 1][3][kw] = a3;
        }
    }
    __syncthreads();
    if (sub == 0 && kw < KEEP) {
        a0 += ps[0][0][kw] + ps[1][0][kw] + ps[2][0][kw];
        a1 += ps[0][1][kw] + ps[1][1][kw] + ps[2][1][kw];
        a2 += ps[0][2][kw] + ps[1][2][kw] + ps[2][2][kw];
        a3 += ps[0][3][kw] + ps[1][3][kw] + ps[2][3][kw];
        float* X = Xd + ((size_t)b * KEEP + kh0) * KEEP + kw;
        X[0] = a0; X[112] = a1; X[224] = a2; X[336] = a3;
    }
}

// ---- conv1 + BN + ReLU on [0,115)^2 -> channel-last bf16 h1c[b][r][c][64] ----
__global__ __launch_bounds__(256) void conv1_kernel(const float* __restrict__ Xd,
                                                    const float* __restrict__ ws1,
                                                    const float* __restrict__ wb1,
                                                    unsigned short* __restrict__ h1c) {
    const int r = blockIdx.y, b = blockIdx.z;
    const int c0 = blockIdx.x * 32;
    const int tid = threadIdx.x;
    __shared__ float xs[3][36];       // rows r-1..r+1, cols c0-1..c0+32
    __shared__ float wsm[8][73];      // [icg][(ic&7)*9+t], +pad for bank spread
    __shared__ float wbs[64];
    const float* X = Xd + (size_t)b * KEEP * KEEP;
    for (int i = tid; i < 102; i += 256) {
        int dr = i / 34, dc = i - dr * 34;
        int rr = r - 1 + dr, cc = c0 - 1 + dc;
        xs[dr][dc] = ((unsigned)rr < (unsigned)KEEP && (unsigned)cc < (unsigned)KEEP)
                         ? X[rr * KEEP + cc] : 0.f;
    }
    for (int i = tid; i < 576; i += 256) {
        int ic = i / 9, t = i - ic * 9;
        wsm[ic >> 3][(ic & 7) * 9 + t] = ws1[i];
    }
    if (tid < 64) wbs[tid] = wb1[tid];
    __syncthreads();

    const int px = tid >> 3, icg = tid & 7;
    const int c = c0 + px;
    float xv[9];
#pragma unroll
    for (int ky = 0; ky < 3; ++ky)
#pragma unroll
        for (int kx = 0; kx < 3; ++kx) xv[ky * 3 + kx] = xs[ky][px + kx];

    union { unsigned short us[8]; uint4 v; } u;
#pragma unroll
    for (int j = 0; j < 8; ++j) {
        float s = wbs[icg * 8 + j];
#pragma unroll
        for (int t = 0; t < 9; ++t) s = fmaf(xv[t], wsm[icg][j * 9 + t], s);
        u.us[j] = f2bf(fmaxf(s, 0.f));
    }
    if (c < H1DIM) {
        unsigned short* dst = h1c + (((size_t)b * H1DIM + r) * H1DIM + c) * 64 + icg * 8;
        *reinterpret_cast<uint4*>(dst) = u.v;
    }
}

// ---- conv2 via bf16 MFMA: 9-tap shifted implicit GEMM, fused BN+ReLU+A-mask+sum ----
// grid (8 tc, 8 tr, 32 b), block 512 = 8 waves = 4 mg x 2 og.
// Wave: 4 M-frags (rows 4mg..4mg+3) x 4 N-frags (oc og*64..og*64+63).
// 1 ds_read_b128 serves 4 MFMA; B pre-packed lane-contiguous (4x 1KB loads/step).
__global__ __launch_bounds__(512, 4) void conv2_mfma_kernel(
    const unsigned short* __restrict__ h1c, const uint4* __restrict__ w2f,
    const float* __restrict__ b2, const float* __restrict__ g2,
    const float* __restrict__ be2, const float* __restrict__ m2,
    const float* __restrict__ v2, float* __restrict__ partial) {
    const int tc = blockIdx.x, tr = blockIdx.y, b = blockIdx.z;
    const int r0 = tr * 16, c0 = tc * 16;
    const int tid = threadIdx.x;
    const int lane = tid & 63, w = tid >> 6;
    const int mg = w & 3, og = w >> 2;
    const int l15 = lane & 15, h4 = lane >> 4;

    __shared__ unsigned short At[324 * 64];   // 41472 B, XOR-swizzled

    // stage A tile: rows r0-1..r0+16, cols c0-1..c0+16, 64 ic = 8 granules of 16B
    const unsigned short* __restrict__ h1b = h1c + (size_t)b * (H1DIM * H1DIM * 64);
    for (int e = tid; e < 2592; e += 512) {
        int px = e >> 3, gi = e & 7;
        int pr = px / 18, pc = px - pr * 18;
        int gr = r0 + pr - 1, gc = c0 + pc - 1;
        uint4 v = make_uint4(0u, 0u, 0u, 0u);
        if ((unsigned)gr < (unsigned)H1DIM && (unsigned)gc < (unsigned)H1DIM)
            v = *reinterpret_cast<const uint4*>(h1b + ((size_t)(gr * H1DIM + gc)) * 64 + gi * 8);
        *reinterpret_cast<uint4*>(&At[px * 64 + ((gi * 8) ^ ((px & 7) << 3))]) = v;
    }
    __syncthreads();

    f32x4 acc[4][4];
#pragma unroll
    for (int f = 0; f < 4; ++f)
#pragma unroll
        for (int n = 0; n < 4; ++n) acc[f][n] = (f32x4){0.f, 0.f, 0.f, 0.f};

    // rows handled by this wave: r0+4mg .. r0+4mg+3 ; frow = #valid rows (wave-uniform)
    const int flim = ADIM - (r0 + 4 * mg);   // f valid iff f < flim
    if (flim > 0) {
        bf16x8 Bf[2][4];
#define LOADB(buf, t, kc)                                                               \
    {                                                                                   \
        const uint4* bp = w2f + (size_t)(((t) * 2 + (kc)) * 8 + og * 4) * 64 + lane;    \
        Bf[buf][0] = *reinterpret_cast<const bf16x8*>(bp);                              \
        Bf[buf][1] = *reinterpret_cast<const bf16x8*>(bp + 64);                         \
        Bf[buf][2] = *reinterpret_cast<const bf16x8*>(bp + 128);                        \
        Bf[buf][3] = *reinterpret_cast<const bf16x8*>(bp + 192);                        \
    }
        LOADB(0, 0, 0);
#pragma unroll
        for (int s = 0; s < 18; ++s) {
            const int kc = s / 9, t = s - 9 * kc;
            if (s + 1 < 18) {
                const int nk = (s + 1) / 9, nt = (s + 1) - 9 * nk;
                LOADB((s + 1) & 1, nt, nk);
            }
            const int ky = t / 3, kx = t - 3 * ky;
#pragma unroll
            for (int f = 0; f < 4; ++f) {
                if (f < flim) {                      // wave-uniform
                    const int px = (4 * mg + f + ky) * 18 + l15 + kx;
                    const bf16x8 a = *reinterpret_cast<const bf16x8*>(
                        &At[px * 64 + ((kc * 32 + h4 * 8) ^ ((px & 7) << 3))]);
                    acc[f][0] = __builtin_amdgcn_mfma_f32_16x16x32_bf16(a, Bf[s & 1][0], acc[f][0], 0, 0, 0);
                    acc[f][1] = __builtin_amdgcn_mfma_f32_16x16x32_bf16(a, Bf[s & 1][1], acc[f][1], 0, 0, 0);
                    acc[f][2] = __builtin_amdgcn_mfma_f32_16x16x32_bf16(a, Bf[s & 1][2], acc[f][2], 0, 0, 0);
                    acc[f][3] = __builtin_amdgcn_mfma_f32_16x16x32_bf16(a, Bf[s & 1][3], acc[f][3], 0, 0, 0);
                }
            }
        }
#undef LOADB
    }

    // epilogue: BN+ReLU, mask to region A, reduce over pixels, write partials
    const int tile = tr * 8 + tc;
    float* pslice = partial + (((size_t)b * 64 + tile) * 4 + mg) * 128;
#pragma unroll
    for (int n = 0; n < 4; ++n) {
        int oc = og * 64 + n * 16 + l15;
        float sc = g2[oc] * rsqrtf(v2[oc] + 1e-5f);
        float bias = b2[oc] - m2[oc];
        float add = be2[oc];
        float s = 0.f;
#pragma unroll
        for (int f = 0; f < 4; ++f) {
            int row = r0 + 4 * mg + f;
            bool rok = row < ADIM;
#pragma unroll
            for (int i = 0; i < 4; ++i) {
                int col = c0 + (h4 << 2) + i;
                float v = fmaxf(fmaf(acc[f][n][i] + bias, sc, add), 0.f);
                s += (rok && col < ADIM) ? v : 0.f;
            }
        }
        s += __shfl_xor(s, 16);
        s += __shfl_xor(s, 32);
        if (lane < 16) pslice[oc] = s;
    }
}

// ---- reduce partials + analytic constant regions -> mean[b][oc] ----
// grid (32 b, 8 ocg), 256 thr: thread (jq 0..15, ocl 0..15); 16-deep chains.
__global__ __launch_bounds__(256) void reduce_mean_kernel(
    const float* __restrict__ partial, const float* __restrict__ P,
    const float* __restrict__ b2, const float* __restrict__ g2,
    const float* __restrict__ be2, const float* __restrict__ m2,
    const float* __restrict__ v2, float* __restrict__ mean) {
    int b = blockIdx.x, ocg = blockIdx.y;
    int tid = threadIdx.x;
    int ocl = tid & 15, jq = tid >> 4;
    int oc = ocg * 16 + ocl;
    const float* pb = partial + (size_t)b * 256 * 128 + oc;
    float s = 0.f;
#pragma unroll
    for (int jj = 0; jj < 16; ++jj) s += pb[(size_t)(jq * 16 + jj) * 128];
    __shared__ float red[16][17];
    red[jq][ocl] = s;
    __syncthreads();
    if (jq == 0) {
        float tot = 0.f;
#pragma unroll
        for (int k = 0; k < 16; ++k) tot += red[k][ocl];

        float p[9];
#pragma unroll
        for (int t = 0; t < 9; ++t) p[t] = P[oc * 9 + t];

        float Sall = p[0] + p[1] + p[2] + p[3] + p[4] + p[5] + p[6] + p[7] + p[8];
        float Stop = p[3] + p[4] + p[5] + p[6] + p[7] + p[8];
        float Sbot = p[0] + p[1] + p[2] + p[3] + p[4] + p[5];
        float Sleft  = p[1] + p[2] + p[4] + p[5] + p[7] + p[8];
        float Sright = p[0] + p[1] + p[3] + p[4] + p[6] + p[7];
        float Ctr = p[3] + p[4] + p[6] + p[7];
        float Cbl = p[1] + p[2] + p[4] + p[5];
        float Cbr = p[0] + p[1] + p[3] + p[4];

        float bias = b2[oc], mm = m2[oc], bb = be2[oc];
        float sc = g2[oc] * rsqrtf(v2[oc] + 1e-5f);
#define VALOF(S) fmaxf(((bias) + (S) - (mm)) * (sc) + (bb), 0.f)
        float cs = 36515.f * VALOF(Sall) + 109.f * VALOF(Stop) + 109.f * VALOF(Sleft)
                 + 222.f * VALOF(Sbot) + 222.f * VALOF(Sright)
                 + VALOF(Ctr) + VALOF(Cbl) + VALOF(Cbr);
#undef VALOF
        mean[b * 128 + oc] = (tot + cs) * (1.f / (224.f * 224.f));
    }
}

// ---- final linear (float4 weight rows) ----
__global__ __launch_bounds__(256) void final_linear_kernel(const float* __restrict__ mean,
                                                           const float* __restrict__ wp,
                                                           const float* __restrict__ bp,
                                                           float* __restrict__ out) {
    int b = blockIdx.x, e = threadIdx.x;
    __shared__ float mrow[128];
    if (threadIdx.x < 128) mrow[threadIdx.x] = mean[b * 128 + threadIdx.x];
    __syncthreads();
    const float4* wr = reinterpret_cast<const float4*>(wp + (size_t)e * 128);
    float s = bp[e];
#pragma unroll 8
    for (int c = 0; c < 32; ++c) {
        float4 wv = wr[c];
        s = fmaf(mrow[4 * c], wv.x, s);
        s = fmaf(mrow[4 * c + 1], wv.y, s);
        s = fmaf(mrow[4 * c + 2], wv.z, s);
        s = fmaf(mrow[4 * c + 3], wv.w, s);
    }
    out[(size_t)b * 256 + e] = s;
}

extern "C" void kernel_launch(void* const* d_in, const int* in_sizes, int n_in,
                              void* d_out, int out_size, void* d_ws, size_t ws_size,
                              hipStream_t stream) {
    const float* x   = (const float*)d_in[0];
    const float* w1  = (const float*)d_in[1];
    const float* b1  = (const float*)d_in[2];
    const float* g1  = (const float*)d_in[3];
    const float* be1 = (const float*)d_in[4];
    const float* m1  = (const float*)d_in[5];
    const float* v1  = (const float*)d_in[6];
    const float* w2  = (const float*)d_in[7];
    const float* b2  = (const float*)d_in[8];
    const float* g2  = (const float*)d_in[9];
    const float* be2 = (const float*)d_in[10];
    const float* m2  = (const float*)d_in[11];
    const float* v2  = (const float*)d_in[12];
    const float* wp  = (const float*)d_in[13];
    const float* bp  = (const float*)d_in[14];
    float* out = (float*)d_out;

    float* ws = (float*)d_ws;
    size_t off = 0;
    float* Bst  = ws + off; off += (size_t)KEEP * KEEP;          // 12544
    float* tmp1 = ws + off; off += (size_t)32 * NPIX * KEEP;     // 802816
    float* Xd   = ws + off; off += (size_t)32 * KEEP * KEEP;     // 401408
    float* P    = ws + off; off += 128 * 9;
    float* ws1  = ws + off; off += 64 * 9;
    float* wb1  = ws + off; off += 64;
    uint4* w2f  = (uint4*)(ws + off); off += (size_t)9216 * 4;   // 9216 uint4
    float* part = ws + off; off += (size_t)32 * 256 * 128;       // 1048576
    float* mean = ws + off; off += 32 * 128;
    unsigned short* h1c = (unsigned short*)(ws + off);
    off += (size_t)32 * H1DIM * H1DIM * 64 / 2;                  // bf16

    if (ws_size < off * sizeof(float)) return;  // workspace too small: fail visibly

    prep_kernel<<<dim3(91), dim3(256), 0, stream>>>(w1, b1, g1, be1, m1, v1, w2,
                                                    Bst, P, ws1, wb1, w2f);
    dct_w_kernel<<<dim3(32 * 56), dim3(128), 0, stream>>>(x, Bst, tmp1);
    dct_h_kernel<<<dim3(28, 32), dim3(512), 0, stream>>>(tmp1, Bst, Xd);
    conv1_kernel<<<dim3(4, H1DIM, 32), dim3(256), 0, stream>>>(Xd, ws1, wb1, h1c);
    conv2_mfma_kernel<<<dim3(8, 8, 32), dim3(512), 0, stream>>>(
        h1c, w2f, b2, g2, be2, m2, v2, part);
    reduce_mean_kernel<<<dim3(32, 8), dim3(256), 0, stream>>>(part, P, b2, g2, be2, m2, v2, mean);
    final_linear_kernel<<<dim3(32), dim3(256), 0, stream>>>(mean, wp, bp, out);
}